// Round 6
// baseline (242.579 us; speedup 1.0000x reference)
//
#include <hip/hip_runtime.h>
#include <math.h>

#define N_POS 8000
#define C_CH  128
#define KSPLIT 5
#define KT_PER 25      // 125 k-tiles of 64 keys, 25 per split
#define QTILES 125     // q-tiles of 64 queries

typedef __bf16 bf16x8 __attribute__((ext_vector_type(8)));
typedef float  f32x4  __attribute__((ext_vector_type(4)));

#define MFMA(a,b,c) __builtin_amdgcn_mfma_f32_16x16x32_bf16((a),(b),(c),0,0,0)

// MFMA 16x16x32 lane layouts (verified m89/m120):
//   A[m][k]: m = lane&15, k = (lane>>4)*8 + j
//   B[k][n]: n = lane&15, k = (lane>>4)*8 + j
//   D[m][n]: n = lane&15, m = (lane>>4)*4 + reg

#define GLOAD_LDS(gp, lp) \
    __builtin_amdgcn_global_load_lds( \
        (const __attribute__((address_space(1))) void*)(gp), \
        (__attribute__((address_space(3))) void*)(lp), 16, 0, 0)

// ---------------------------------------------------------------------------
// Kernel A: QKV projections via MFMA. grid 250 (n-tiles of 32), block 256.
// (round-1 version, best measured.)
// out rows: o 0..15 -> q, 16..31 -> k, 32..159 -> v(ch=o-32)
// q_bf,k_bf: [n][16] bf16.  v_bf: [c][8000] bf16.
// ---------------------------------------------------------------------------
__global__ __launch_bounds__(256) void qkv_kernel(
    const float* __restrict__ x,
    const float* __restrict__ wq, const float* __restrict__ bq,
    const float* __restrict__ wk, const float* __restrict__ bk,
    const float* __restrict__ wv, const float* __restrict__ bv,
    __bf16* __restrict__ q_bf, __bf16* __restrict__ k_bf, __bf16* __restrict__ v_bf)
{
    __shared__ __bf16 x_lds[32 * 136];          // [n][c]
    __shared__ __bf16 v_out[128 * 36];          // [ch][n]

    const int t    = threadIdx.x;
    const int n0   = blockIdx.x * 32;
    const int lane = t & 63;
    const int w    = t >> 6;
    const int l15  = lane & 15;
    const int quad = lane >> 4;

    // stage x tile [128c x 32n] -> x_lds[n][c] bf16 (transpose+convert)
    for (int r = 0; r < 4; ++r) {
        int f = r * 256 + t;
        int ch = f >> 3, n4 = f & 7;
        float4 xv = *reinterpret_cast<const float4*>(&x[ch * N_POS + n0 + n4 * 4]);
        x_lds[(n4 * 4 + 0) * 136 + ch] = (__bf16)xv.x;
        x_lds[(n4 * 4 + 1) * 136 + ch] = (__bf16)xv.y;
        x_lds[(n4 * 4 + 2) * 136 + ch] = (__bf16)xv.z;
        x_lds[(n4 * 4 + 3) * 136 + ch] = (__bf16)xv.w;
    }

    // A-frags: weight rows fp32->bf16 in regs. wave w owns mtiles {w, w+4, w+8<10}
    bf16x8 aw[3][4];
    f32x4  acc[3][2];
    const int nmt = (w < 2) ? 3 : 2;
    for (int mi = 0; mi < nmt; ++mi) {
        int mt = w + 4 * mi;
        const float *wrow, *brow;
        if (mt == 0)      { wrow = wq + l15 * 128;               brow = bq; }
        else if (mt == 1) { wrow = wk + l15 * 128;               brow = bk; }
        else              { wrow = wv + ((mt - 2) * 16 + l15) * 128;
                            brow = bv + (mt - 2) * 16; }
        for (int ks = 0; ks < 4; ++ks) {
            float4 f0 = *reinterpret_cast<const float4*>(wrow + ks * 32 + quad * 8);
            float4 f1 = *reinterpret_cast<const float4*>(wrow + ks * 32 + quad * 8 + 4);
            bf16x8 a;
            a[0]=(__bf16)f0.x; a[1]=(__bf16)f0.y; a[2]=(__bf16)f0.z; a[3]=(__bf16)f0.w;
            a[4]=(__bf16)f1.x; a[5]=(__bf16)f1.y; a[6]=(__bf16)f1.z; a[7]=(__bf16)f1.w;
            aw[mi][ks] = a;
        }
        for (int ni = 0; ni < 2; ++ni) {
            acc[mi][ni][0] = brow[quad * 4 + 0]; acc[mi][ni][1] = brow[quad * 4 + 1];
            acc[mi][ni][2] = brow[quad * 4 + 2]; acc[mi][ni][3] = brow[quad * 4 + 3];
        }
    }
    __syncthreads();

    for (int ks = 0; ks < 4; ++ks) {
        bf16x8 b0 = *reinterpret_cast<const bf16x8*>(&x_lds[(0  + l15) * 136 + ks * 32 + quad * 8]);
        bf16x8 b1 = *reinterpret_cast<const bf16x8*>(&x_lds[(16 + l15) * 136 + ks * 32 + quad * 8]);
        for (int mi = 0; mi < nmt; ++mi) {
            acc[mi][0] = MFMA(aw[mi][ks], b0, acc[mi][0]);
            acc[mi][1] = MFMA(aw[mi][ks], b1, acc[mi][1]);
        }
    }

    union S4 { short4 s; __bf16 b[4]; };
    for (int mi = 0; mi < nmt; ++mi) {
        int mt = w + 4 * mi;
        for (int ni = 0; ni < 2; ++ni) {
            S4 u;
            u.b[0]=(__bf16)acc[mi][ni][0]; u.b[1]=(__bf16)acc[mi][ni][1];
            u.b[2]=(__bf16)acc[mi][ni][2]; u.b[3]=(__bf16)acc[mi][ni][3];
            int n = n0 + ni * 16 + l15;
            if (mt == 0) {
                *reinterpret_cast<short4*>(&q_bf[n * 16 + quad * 4]) = u.s;
            } else if (mt == 1) {
                *reinterpret_cast<short4*>(&k_bf[n * 16 + quad * 4]) = u.s;
            } else {
                int ch0 = (mt - 2) * 16 + quad * 4;
                int nl  = ni * 16 + l15;
                v_out[(ch0 + 0) * 36 + nl] = u.b[0];
                v_out[(ch0 + 1) * 36 + nl] = u.b[1];
                v_out[(ch0 + 2) * 36 + nl] = u.b[2];
                v_out[(ch0 + 3) * 36 + nl] = u.b[3];
            }
        }
    }
    __syncthreads();
    for (int r = 0; r < 4; ++r) {
        int f = r * 256 + t;
        int ch = f >> 3, n4 = f & 7;
        int2 d = *reinterpret_cast<const int2*>(&v_out[ch * 36 + n4 * 4]);
        *reinterpret_cast<int2*>(&v_bf[ch * N_POS + n0 + n4 * 4]) = d;
    }
}

// ---------------------------------------------------------------------------
// Kernel B v6: fused attention, split-K, with LAST-BLOCK-WINS reduce.
// Core loop = v5 (one barrier/k-tile, counted vmcnt(5), K in regs, V via
// wave-self gload_lds, P double-buffered in LDS).  New: after writing its
// av_part/l_part partials, each block does device-scope release
// (__threadfence) + atomicAdd on cnt[qt]; the 5th arriver re-reads all 5
// splits' partials (just written -> L2-resident, 40-load ILP), sums,
// normalizes by 1/sum(l), and writes av_bf[n][c] bf16.  This moves the
// 20.5 MB split-K reduce out of proj_out (measured there: 57 us tile-16,
// VALUBusy 1.9% -- pure latency chain) and hides it under attn's own
// completion skew.
// ---------------------------------------------------------------------------
__global__ __launch_bounds__(256, 3) void attn_kernel(
    const __bf16* __restrict__ q_bf, const __bf16* __restrict__ k_bf,
    const __bf16* __restrict__ v_bf, float* __restrict__ av_part,
    float* __restrict__ l_part, int* __restrict__ cnt,
    __bf16* __restrict__ av_bf)
{
    __shared__ __bf16 v_buf[2][8192];   // 16 KB each
    __shared__ __bf16 p_lds[2][4096];   // 8 KB each

    const int t    = threadIdx.x;
    const int qt   = blockIdx.x % QTILES;
    const int sp   = blockIdx.x / QTILES;
    const int n0q  = qt * 64;
    const int lane = t & 63;
    const int w    = t >> 6;
    const int l15  = lane & 15;
    const int quad = lane >> 4;

    // V staging map (per lane, loop-invariant)
    const int chL   = lane >> 3;              // low 3 bits of channel
    const int vpart = (lane & 7) ^ chL;       // key-octet (XOR swizzle)

    // Q B-frags in registers (k-dim 16 padded to 32 with zeros), 4 q-groups
    bf16x8 aq[4];
    for (int ni = 0; ni < 4; ++ni) {
        for (int j = 0; j < 8; ++j) aq[ni][j] = (__bf16)0.0f;
        if (quad < 2)
            aq[ni] = *reinterpret_cast<const bf16x8*>(
                &q_bf[(n0q + ni * 16 + l15) * 16 + quad * 8]);
    }

    f32x4 acc[2][4];
    for (int mi = 0; mi < 2; ++mi)
        for (int ni = 0; ni < 4; ++ni)
            for (int r = 0; r < 4; ++r) acc[mi][ni][r] = 0.f;
    float lp[4] = {0.f, 0.f, 0.f, 0.f};

    const int kt0   = sp * KT_PER;
    const int ktEnd = kt0 + KT_PER;

    // stage one tile's V: 4 gload_lds per wave, self-consumed rows
    auto stageV = [&](int kt) {
        const int n0k = kt * 64;
        __bf16* vb = &v_buf[kt & 1][0];
        for (int r = 0; r < 4; ++r) {
            int R = w * 4 + r;   // wave-uniform LDS base; ch 8R..8R+7
            GLOAD_LDS(v_bf + (8 * R + chL) * N_POS + n0k + vpart * 8,
                      &vb[R * 512]);
        }
    };

    // K double-buffer in regs (zero-init once; lanes 32-63 stay zero forever)
    bf16x8 kA, kB;
    for (int j = 0; j < 8; ++j) { kA[j] = (__bf16)0.0f; kB[j] = (__bf16)0.0f; }

    stageV(kt0);
    if (quad < 2)
        kA = *reinterpret_cast<const bf16x8*>(
            &k_bf[(size_t)(kt0 * 64 + w * 16 + l15) * 16 + quad * 8]);

    const int oS  = w * 2 + (quad >> 1);   // P-write octet
    const int sub = (quad & 1) * 4;        // P-write elem offset in chunk

    union S4 { short4 sh; __bf16 b[4]; };

    auto iter = [&](int kt, bf16x8& kc, bf16x8& kn, int pbuf) {
        const bool last = (kt + 1 >= ktEnd);
        if (!last) {
            stageV(kt + 1);
            if (quad < 2)
                kn = *reinterpret_cast<const bf16x8*>(
                    &k_bf[(size_t)((kt + 1) * 64 + w * 16 + l15) * 16 + quad * 8]);
            asm volatile("s_waitcnt vmcnt(5)" ::: "memory");
        } else {
            asm volatile("s_waitcnt vmcnt(0)" ::: "memory");
        }
        __builtin_amdgcn_sched_barrier(0);

        // ---- S phase: A = K regs (wave w -> keys w*16..+15), B = Q regs
        __bf16* pb = &p_lds[pbuf][0];
#pragma unroll
        for (int ni = 0; ni < 4; ++ni) {
            f32x4 s;
            for (int r = 0; r < 4; ++r) s[r] = 0.f;
            s = MFMA(kc, aq[ni], s);           // D[m=key][n=q]
            S4 u;
            u.b[0] = (__bf16)__expf(s[0]); u.b[1] = (__bf16)__expf(s[1]);
            u.b[2] = (__bf16)__expf(s[2]); u.b[3] = (__bf16)__expf(s[3]);
            *reinterpret_cast<short4*>(
                &pb[(oS * 64 + ni * 16 + l15) * 8 + sub]) = u.sh;
            // l partial: per-lane sum of QUANTIZED p (this lane's 4 keys)
            lp[ni] += (float)u.b[0] + (float)u.b[1]
                    + (float)u.b[2] + (float)u.b[3];
        }

        // single barrier: P[pbuf] visible; prefetch stays in flight
        asm volatile("s_waitcnt lgkmcnt(0)" ::: "memory");
        __builtin_amdgcn_s_barrier();
        __builtin_amdgcn_sched_barrier(0);

        // ---- PV phase: wave w owns ch-tiles {2w, 2w+1} (self-staged V)
        const __bf16* vb = &v_buf[kt & 1][0];
        const __bf16* pr = &p_lds[pbuf][0];
        const int chl = l15 & 7;
#pragma unroll
        for (int ks = 0; ks < 2; ++ks) {
            int pz = ((ks * 4 + quad) ^ chl);
            bf16x8 a0 = *reinterpret_cast<const bf16x8*>(
                &vb[(((2 * w)     * 2 + (l15 >> 3)) * 64 + chl * 8 + pz) * 8]);
            bf16x8 a1 = *reinterpret_cast<const bf16x8*>(
                &vb[(((2 * w + 1) * 2 + (l15 >> 3)) * 64 + chl * 8 + pz) * 8]);
            const int ob = (ks * 4 + quad) * 64;
            bf16x8 p0 = *reinterpret_cast<const bf16x8*>(&pr[(ob +  0 + l15) * 8]);
            bf16x8 p1 = *reinterpret_cast<const bf16x8*>(&pr[(ob + 16 + l15) * 8]);
            bf16x8 p2 = *reinterpret_cast<const bf16x8*>(&pr[(ob + 32 + l15) * 8]);
            bf16x8 p3 = *reinterpret_cast<const bf16x8*>(&pr[(ob + 48 + l15) * 8]);
            acc[0][0] = MFMA(a0, p0, acc[0][0]);
            acc[0][1] = MFMA(a0, p1, acc[0][1]);
            acc[0][2] = MFMA(a0, p2, acc[0][2]);
            acc[0][3] = MFMA(a0, p3, acc[0][3]);
            acc[1][0] = MFMA(a1, p0, acc[1][0]);
            acc[1][1] = MFMA(a1, p1, acc[1][1]);
            acc[1][2] = MFMA(a1, p2, acc[1][2]);
            acc[1][3] = MFMA(a1, p3, acc[1][3]);
        }
    };

    for (int i = 0; i < KT_PER; i += 2) {
        iter(kt0 + i, kA, kB, 0);
        if (i + 1 < KT_PER) iter(kt0 + i + 1, kB, kA, 1);
    }

    // epilogue: quad-reduce lp, cross-wave l reduction via LDS scratch
    __syncthreads();
    float* lsh = reinterpret_cast<float*>(&p_lds[0][0]);   // 256 floats
    float lt[4];
#pragma unroll
    for (int ni = 0; ni < 4; ++ni) {
        float ps = lp[ni];
        ps += __shfl_xor(ps, 16, 64);
        ps += __shfl_xor(ps, 32, 64);
        lt[ni] = ps;
    }
    if (quad == 0) {
#pragma unroll
        for (int ni = 0; ni < 4; ++ni)
            lsh[w * 64 + ni * 16 + l15] = lt[ni];
    }
    __syncthreads();

    // write av partials: av_part[sp][n][c] fp32
    float* dst = av_part + (size_t)sp * 1024000;
    for (int mi = 0; mi < 2; ++mi)
        for (int ni = 0; ni < 4; ++ni) {
            int n  = n0q + ni * 16 + l15;
            int ch = (2 * w + mi) * 16 + quad * 4;
            *reinterpret_cast<f32x4*>(&dst[n * 128 + ch]) = acc[mi][ni];
        }
    if (t < 64)
        l_part[sp * N_POS + n0q + t] =
            lsh[t] + lsh[64 + t] + lsh[128 + t] + lsh[192 + t];

    // ---- last-block-wins split-K reduce (release/acquire via threadfence) --
    __threadfence();                       // release: partials visible device-wide
    __shared__ int last_flag;
    if (t == 0) {
        int prev = atomicAdd(&cnt[qt], 1);
        last_flag = (prev == KSPLIT - 1) ? 1 : 0;
    }
    __syncthreads();
    if (!last_flag) return;
    __threadfence();                       // acquire: see other splits' writes

    // winner: 64 rows x 16 c-octets = 1024 octets, 4/thread, 40-load ILP
#pragma unroll
    for (int r = 0; r < 4; ++r) {
        int g   = r * 256 + t;
        int row = g >> 4, oc = g & 15;
        int n   = n0q + row;
        float l = 0.f;
#pragma unroll
        for (int s = 0; s < KSPLIT; ++s) l += l_part[s * N_POS + n];
        float4 a0 = make_float4(0.f, 0.f, 0.f, 0.f);
        float4 a1 = make_float4(0.f, 0.f, 0.f, 0.f);
#pragma unroll
        for (int s = 0; s < KSPLIT; ++s) {
            const float* p = av_part + (size_t)s * 1024000 + n * 128 + oc * 8;
            float4 u = *reinterpret_cast<const float4*>(p);
            float4 v = *reinterpret_cast<const float4*>(p + 4);
            a0.x += u.x; a0.y += u.y; a0.z += u.z; a0.w += u.w;
            a1.x += v.x; a1.y += v.y; a1.z += v.z; a1.w += v.w;
        }
        float inv = 1.f / l;
        union { int4 iv; __bf16 b[8]; } u;
        u.b[0]=(__bf16)(a0.x*inv); u.b[1]=(__bf16)(a0.y*inv);
        u.b[2]=(__bf16)(a0.z*inv); u.b[3]=(__bf16)(a0.w*inv);
        u.b[4]=(__bf16)(a1.x*inv); u.b[5]=(__bf16)(a1.y*inv);
        u.b[6]=(__bf16)(a1.z*inv); u.b[7]=(__bf16)(a1.w*inv);
        *reinterpret_cast<int4*>(&av_bf[n * 128 + oc * 8]) = u.iv;
    }
}

// ---------------------------------------------------------------------------
// Kernel C: y = wa @ av + ba (MFMA) + BN stats.  grid 250 (n-tile 32).
// Lean version: reads pre-normalized bf16 av (built by attn's winner blocks,
// L2-hot), no split-K reduce here.
// ---------------------------------------------------------------------------
__global__ __launch_bounds__(256) void proj_out_kernel(
    const __bf16* __restrict__ av_bf,
    const float* __restrict__ wa, const float* __restrict__ ba,
    float* __restrict__ y_ws, float* __restrict__ bn_sum, float* __restrict__ bn_sumsq)
{
    __shared__ __bf16 b_lds[4096];   // 32n x 128c fragment-packed, swizzled

    const int t    = threadIdx.x;
    const int n0   = blockIdx.x * 32;
    const int lane = t & 63;
    const int w    = t >> 6;
    const int l15  = lane & 15;
    const int quad = lane >> 4;

    // build B tile: 512 c-octets, 2 per thread (coalesced 16B reads, L2-hot)
    for (int r = 0; r < 2; ++r) {
        int g = r * 256 + t;
        int n = g >> 4, oc = g & 15;
        int4 u = *reinterpret_cast<const int4*>(&av_bf[(n0 + n) * 128 + oc * 8]);
        int A = (n >> 4) * 16 + oc;
        int slot = (n & 15) ^ (oc & 7);
        *reinterpret_cast<int4*>(&b_lds[(A * 16 + slot) * 8]) = u;
    }

    // A-frags: wa rows for mtiles {2w, 2w+1}
    bf16x8 aw[2][4];
    f32x4  acc[2][2];
    for (int mi = 0; mi < 2; ++mi) {
        int mt = 2 * w + mi;
        const float* wrow = wa + (mt * 16 + l15) * 128;
        for (int ks = 0; ks < 4; ++ks) {
            float4 f0 = *reinterpret_cast<const float4*>(wrow + ks * 32 + quad * 8);
            float4 f1 = *reinterpret_cast<const float4*>(wrow + ks * 32 + quad * 8 + 4);
            bf16x8 a;
            a[0]=(__bf16)f0.x; a[1]=(__bf16)f0.y; a[2]=(__bf16)f0.z; a[3]=(__bf16)f0.w;
            a[4]=(__bf16)f1.x; a[5]=(__bf16)f1.y; a[6]=(__bf16)f1.z; a[7]=(__bf16)f1.w;
            aw[mi][ks] = a;
        }
        for (int ni = 0; ni < 2; ++ni) {
            acc[mi][ni][0] = ba[mt * 16 + quad * 4 + 0];
            acc[mi][ni][1] = ba[mt * 16 + quad * 4 + 1];
            acc[mi][ni][2] = ba[mt * 16 + quad * 4 + 2];
            acc[mi][ni][3] = ba[mt * 16 + quad * 4 + 3];
        }
    }
    __syncthreads();

    for (int ks = 0; ks < 4; ++ks) {
        int oc = ks * 4 + quad;
        int slot = l15 ^ (oc & 7);
        bf16x8 b0 = *reinterpret_cast<const bf16x8*>(&b_lds[((0  + oc) * 16 + slot) * 8]);
        bf16x8 b1 = *reinterpret_cast<const bf16x8*>(&b_lds[((16 + oc) * 16 + slot) * 8]);
        for (int mi = 0; mi < 2; ++mi) {
            acc[mi][0] = MFMA(aw[mi][ks], b0, acc[mi][0]);
            acc[mi][1] = MFMA(aw[mi][ks], b1, acc[mi][1]);
        }
    }

    // y writes [c][n] + BN partial stats
    for (int mi = 0; mi < 2; ++mi) {
        for (int r = 0; r < 4; ++r) {
            int ch = (2 * w + mi) * 16 + quad * 4 + r;
            float v0 = acc[mi][0][r];
            float v1 = acc[mi][1][r];
            y_ws[ch * N_POS + n0 + 0  + l15] = v0;
            y_ws[ch * N_POS + n0 + 16 + l15] = v1;
            float s1 = v0 + v1;
            float s2 = v0 * v0 + v1 * v1;
#pragma unroll
            for (int off = 8; off >= 1; off >>= 1) {
                s1 += __shfl_xor(s1, off, 64);
                s2 += __shfl_xor(s2, off, 64);
            }
            if (l15 == 0) {
                atomicAdd(&bn_sum[ch],   s1);
                atomicAdd(&bn_sumsq[ch], s2);
            }
        }
    }
}

// ---------------------------------------------------------------------------
// Kernel D: BatchNorm (training stats) + ReLU + residual. grid 1000, block 256.
// ---------------------------------------------------------------------------
__global__ __launch_bounds__(256) void bn_relu_kernel(
    const float* __restrict__ y_ws, const float* __restrict__ x,
    const float* __restrict__ bn_sum, const float* __restrict__ bn_sumsq,
    const float* __restrict__ bn_w, const float* __restrict__ bn_b,
    float* __restrict__ out)
{
    const int i4 = blockIdx.x * 256 + threadIdx.x;
    const int c  = i4 / 2000;
    const float mean  = bn_sum[c]   * (1.f / 8000.f);
    const float var   = bn_sumsq[c] * (1.f / 8000.f) - mean * mean;
    const float rstd  = rsqrtf(var + 1e-5f);
    const float scale = bn_w[c] * rstd;
    const float shift = bn_b[c] - mean * scale;

    float4 y4 = reinterpret_cast<const float4*>(y_ws)[i4];
    float4 x4 = reinterpret_cast<const float4*>(x)[i4];
    float4 o4;
    o4.x = fmaxf(y4.x * scale + shift, 0.f) + x4.x;
    o4.y = fmaxf(y4.y * scale + shift, 0.f) + x4.y;
    o4.z = fmaxf(y4.z * scale + shift, 0.f) + x4.z;
    o4.w = fmaxf(y4.w * scale + shift, 0.f) + x4.w;
    reinterpret_cast<float4*>(out)[i4] = o4;
}

// ---------------------------------------------------------------------------
extern "C" void kernel_launch(void* const* d_in, const int* in_sizes, int n_in,
                              void* d_out, int out_size, void* d_ws, size_t ws_size,
                              hipStream_t stream)
{
    const float* x    = (const float*)d_in[0];
    const float* wq   = (const float*)d_in[1];
    const float* bq   = (const float*)d_in[2];
    const float* wk   = (const float*)d_in[3];
    const float* bk   = (const float*)d_in[4];
    const float* wv   = (const float*)d_in[5];
    const float* bv   = (const float*)d_in[6];
    const float* wa   = (const float*)d_in[7];
    const float* ba   = (const float*)d_in[8];
    const float* bn_w = (const float*)d_in[9];
    const float* bn_b = (const float*)d_in[10];
    float* out = (float*)d_out;

    char* base = (char*)d_ws;
    // byte layout (~29.4 MB):
    float*  av_part = (float*)base;                    // 20,480,000 B (5 x 8000 x 128 f32)
    __bf16* q_bf    = (__bf16*)(base + 20480000);      //    256,000 B
    __bf16* k_bf    = (__bf16*)(base + 20736000);      //    256,000 B
    __bf16* v_bf    = (__bf16*)(base + 20992000);      //  2,048,000 B
    float*  l_part  = (float*)(base + 23040000);       //    160,000 B
    float*  bn_sum   = (float*)(base + 23200000);      //        512 B
    float*  bn_sumsq = bn_sum + 128;                   //        512 B
    float*  y_ws    = (float*)(base + 23201024);       //  4,096,000 B
    __bf16* av_bf   = (__bf16*)(base + 27297024);      //  2,048,000 B
    int*    cnt     = (int*)(base + 29345024);         //        512 B (125 used)

    hipMemsetAsync(bn_sum, 0, 1024, stream);
    hipMemsetAsync(cnt, 0, 512, stream);
    qkv_kernel<<<250, 256, 0, stream>>>(x, wq, bq, wk, bk, wv, bv, q_bf, k_bf, v_bf);
    attn_kernel<<<QTILES * KSPLIT, 256, 0, stream>>>(q_bf, k_bf, v_bf, av_part, l_part, cnt, av_bf);
    proj_out_kernel<<<250, 256, 0, stream>>>(av_bf, wa, ba, y_ws, bn_sum, bn_sumsq);
    bn_relu_kernel<<<1000, 256, 0, stream>>>(y_ws, x, bn_sum, bn_sumsq, bn_w, bn_b, out);
}

// Round 8
// 214.273 us; speedup vs baseline: 1.1321x; 1.1321x over previous
//
#include <hip/hip_runtime.h>
#include <math.h>

#define N_POS 8000
#define C_CH  128
#define KSPLIT 5
#define KT_PER 25      // 125 k-tiles of 64 keys, 25 per split
#define QTILES 125     // q-tiles of 64 queries

typedef __bf16 bf16x8 __attribute__((ext_vector_type(8)));
typedef float  f32x4  __attribute__((ext_vector_type(4)));

#define MFMA(a,b,c) __builtin_amdgcn_mfma_f32_16x16x32_bf16((a),(b),(c),0,0,0)

// MFMA 16x16x32 lane layouts (verified m89/m120):
//   A[m][k]: m = lane&15, k = (lane>>4)*8 + j
//   B[k][n]: n = lane&15, k = (lane>>4)*8 + j
//   D[m][n]: n = lane&15, m = (lane>>4)*4 + reg

#define GLOAD_LDS(gp, lp) \
    __builtin_amdgcn_global_load_lds( \
        (const __attribute__((address_space(1))) void*)(gp), \
        (__attribute__((address_space(3))) void*)(lp), 16, 0, 0)

// ---------------------------------------------------------------------------
// Kernel A: QKV projections via MFMA. grid 250, block 512 (8 waves).
// v7: same algorithm as round-1, but 512 threads -> 2 waves/SIMD so the
// x-staging latency phase has 2x outstanding loads (grid is pinned at 250
// n-tiles < 256 CUs, so blocks/CU can never exceed 1; waves/SIMD is the
// only occupancy lever).  Wave w owns mtiles {w} (+{w+8} for w<2).
// out rows: o 0..15 -> q, 16..31 -> k, 32..159 -> v(ch=o-32)
// ---------------------------------------------------------------------------
__global__ __launch_bounds__(512) void qkv_kernel(
    const float* __restrict__ x,
    const float* __restrict__ wq, const float* __restrict__ bq,
    const float* __restrict__ wk, const float* __restrict__ bk,
    const float* __restrict__ wv, const float* __restrict__ bv,
    __bf16* __restrict__ q_bf, __bf16* __restrict__ k_bf, __bf16* __restrict__ v_bf)
{
    __shared__ __bf16 x_lds[32 * 136];          // [n][c]
    __shared__ __bf16 v_out[128 * 36];          // [ch][n]

    const int t    = threadIdx.x;
    const int n0   = blockIdx.x * 32;
    const int lane = t & 63;
    const int w    = t >> 6;                    // 0..7
    const int l15  = lane & 15;
    const int quad = lane >> 4;

    // stage x tile [128c x 32n] -> x_lds[n][c] bf16 (transpose+convert)
    for (int r = 0; r < 2; ++r) {
        int f = r * 512 + t;                    // 0..1023
        int ch = f >> 3, n4 = f & 7;
        float4 xv = *reinterpret_cast<const float4*>(&x[ch * N_POS + n0 + n4 * 4]);
        x_lds[(n4 * 4 + 0) * 136 + ch] = (__bf16)xv.x;
        x_lds[(n4 * 4 + 1) * 136 + ch] = (__bf16)xv.y;
        x_lds[(n4 * 4 + 2) * 136 + ch] = (__bf16)xv.z;
        x_lds[(n4 * 4 + 3) * 136 + ch] = (__bf16)xv.w;
    }

    // A-frags: weight rows fp32->bf16 in regs. wave w owns mt=w (+ mt=w+8 if w<2)
    bf16x8 aw[2][4];
    f32x4  acc[2][2];
    const int nmt = (w < 2) ? 2 : 1;
    for (int mi = 0; mi < nmt; ++mi) {
        int mt = w + 8 * mi;
        const float *wrow, *brow;
        if (mt == 0)      { wrow = wq + l15 * 128;               brow = bq; }
        else if (mt == 1) { wrow = wk + l15 * 128;               brow = bk; }
        else              { wrow = wv + ((mt - 2) * 16 + l15) * 128;
                            brow = bv + (mt - 2) * 16; }
        for (int ks = 0; ks < 4; ++ks) {
            float4 f0 = *reinterpret_cast<const float4*>(wrow + ks * 32 + quad * 8);
            float4 f1 = *reinterpret_cast<const float4*>(wrow + ks * 32 + quad * 8 + 4);
            bf16x8 a;
            a[0]=(__bf16)f0.x; a[1]=(__bf16)f0.y; a[2]=(__bf16)f0.z; a[3]=(__bf16)f0.w;
            a[4]=(__bf16)f1.x; a[5]=(__bf16)f1.y; a[6]=(__bf16)f1.z; a[7]=(__bf16)f1.w;
            aw[mi][ks] = a;
        }
        for (int ni = 0; ni < 2; ++ni) {
            acc[mi][ni][0] = brow[quad * 4 + 0]; acc[mi][ni][1] = brow[quad * 4 + 1];
            acc[mi][ni][2] = brow[quad * 4 + 2]; acc[mi][ni][3] = brow[quad * 4 + 3];
        }
    }
    __syncthreads();

    for (int ks = 0; ks < 4; ++ks) {
        bf16x8 b0 = *reinterpret_cast<const bf16x8*>(&x_lds[(0  + l15) * 136 + ks * 32 + quad * 8]);
        bf16x8 b1 = *reinterpret_cast<const bf16x8*>(&x_lds[(16 + l15) * 136 + ks * 32 + quad * 8]);
        for (int mi = 0; mi < nmt; ++mi) {
            acc[mi][0] = MFMA(aw[mi][ks], b0, acc[mi][0]);
            acc[mi][1] = MFMA(aw[mi][ks], b1, acc[mi][1]);
        }
    }

    union S4 { short4 s; __bf16 b[4]; };
    for (int mi = 0; mi < nmt; ++mi) {
        int mt = w + 8 * mi;
        for (int ni = 0; ni < 2; ++ni) {
            S4 u;
            u.b[0]=(__bf16)acc[mi][ni][0]; u.b[1]=(__bf16)acc[mi][ni][1];
            u.b[2]=(__bf16)acc[mi][ni][2]; u.b[3]=(__bf16)acc[mi][ni][3];
            int n = n0 + ni * 16 + l15;
            if (mt == 0) {
                *reinterpret_cast<short4*>(&q_bf[n * 16 + quad * 4]) = u.s;
            } else if (mt == 1) {
                *reinterpret_cast<short4*>(&k_bf[n * 16 + quad * 4]) = u.s;
            } else {
                int ch0 = (mt - 2) * 16 + quad * 4;
                int nl  = ni * 16 + l15;
                v_out[(ch0 + 0) * 36 + nl] = u.b[0];
                v_out[(ch0 + 1) * 36 + nl] = u.b[1];
                v_out[(ch0 + 2) * 36 + nl] = u.b[2];
                v_out[(ch0 + 3) * 36 + nl] = u.b[3];
            }
        }
    }
    __syncthreads();
    for (int r = 0; r < 2; ++r) {
        int f = r * 512 + t;                    // 0..1023
        int ch = f >> 3, n4 = f & 7;
        int2 d = *reinterpret_cast<const int2*>(&v_out[ch * 36 + n4 * 4]);
        *reinterpret_cast<int2*>(&v_bf[ch * N_POS + n0 + n4 * 4]) = d;
    }
}

// ---------------------------------------------------------------------------
// Kernel B: fused attention, split-K, MFMA, global_load_lds double-buffer.
// (round-1 version, best measured ~39 us; later variants neutral or worse.)
//
// Per iter:
//   __syncthreads (barrier_A, vmcnt(0)): tile-kt DMA drained -- issued a FULL
//     iteration ago, so the drain is cheap; prev PV LDS reads done.
//   issue tile kt+1 DMA into buf^1 (safe: buf^1 last read before barrier_A)
//   S phase: S = K^T Q (K=16 padded to 32), exp -> p_lds (chunked layout)
//   s_waitcnt lgkmcnt(0) + raw s_barrier (barrier_B): P visible, DMA in flight
//   PV phase: acc += V * P   (XOR-swizzled V chunks, conflict-free b128 reads)
//
// LDS chunk maps (lane-sequential DMA dests, conflict-free fragment reads):
//   V chunk(ch,part) at ((ch>>3)*64 + (ch&7)*8 + (part^(ch&7)))*16B
//   K [key][dim16] contiguous (32B/key); upper k-half of A-frag zero in regs
//   P chunk(q,octet) at (octet*64 + q)*16B   (octet = key>>3, q = 0..63)
// ---------------------------------------------------------------------------
__global__ __launch_bounds__(256, 3) void attn_kernel(
    const __bf16* __restrict__ q_bf, const __bf16* __restrict__ k_bf,
    const __bf16* __restrict__ v_bf, float* __restrict__ av_part,
    float* __restrict__ l_part)
{
    __shared__ __bf16 v_buf[2][8192];   // 16 KB each
    __shared__ __bf16 k_buf[2][1024];   // 2 KB each
    __shared__ __bf16 p_lds[4096];      // 8 KB; total 45056 B -> 3 blocks/CU

    const int t    = threadIdx.x;
    const int qt   = blockIdx.x % QTILES;
    const int sp   = blockIdx.x / QTILES;
    const int n0q  = qt * 64;
    const int lane = t & 63;
    const int w    = t >> 6;
    const int l15  = lane & 15;
    const int quad = lane >> 4;

    // staging maps (per lane, loop-invariant)
    const int chL   = lane >> 3;              // V: low 3 bits of channel
    const int vpart = (lane & 7) ^ chL;       // V: key-octet (XOR swizzle)
    const int kkey  = lane >> 1;              // K: key within 32-key half
    const int khalf = lane & 1;               // K: dim half

    // Q B-frags in registers (k-dim 16 padded to 32 with zeros), 4 q-groups
    bf16x8 aq[4];
    for (int ni = 0; ni < 4; ++ni) {
        for (int j = 0; j < 8; ++j) aq[ni][j] = (__bf16)0.0f;
        if (quad < 2)
            aq[ni] = *reinterpret_cast<const bf16x8*>(
                &q_bf[(n0q + ni * 16 + l15) * 16 + quad * 8]);
    }
    bf16x8 ones;
    for (int j = 0; j < 8; ++j) ones[j] = (__bf16)1.0f;

    f32x4 acc[2][4];
    for (int mi = 0; mi < 2; ++mi)
        for (int ni = 0; ni < 4; ++ni)
            for (int r = 0; r < 4; ++r) acc[mi][ni][r] = 0.f;
    f32x4 lacc;
    for (int r = 0; r < 4; ++r) lacc[r] = 0.f;

    const int kt0 = sp * KT_PER;

    // issue one tile's staging DMA: 4 V ops per wave; K ops on waves 0,1 only
    auto stage = [&](int kt, int buf) {
        const int n0k = kt * 64;
        for (int r = 0; r < 4; ++r) {
            int R = w * 4 + r;   // wave-uniform LDS base
            GLOAD_LDS(v_bf + (8 * R + chL) * N_POS + n0k + vpart * 8,
                      &v_buf[buf][R * 512]);
        }
        if (w < 2)
            GLOAD_LDS(k_bf + (size_t)(n0k + w * 32 + kkey) * 16 + khalf * 8,
                      &k_buf[buf][w * 512]);
    };

    stage(kt0, 0);

    const int oS  = w * 2 + (quad >> 1);   // P-write octet
    const int sub = (quad & 1) * 4;        // P-write elem offset in chunk

    union S4 { short4 sh; __bf16 b[4]; };

    for (int kt = kt0; kt < kt0 + KT_PER; ++kt) {
        const int cur = (kt - kt0) & 1;
        __syncthreads();   // barrier_A: vmcnt(0) drain of tile-kt DMA (1 iter of cover)

        // issue next tile's DMA NOW -> in flight across S + barrier_B + PV
        if (kt + 1 < kt0 + KT_PER) stage(kt + 1, cur ^ 1);

        // ---- S phase: A = K rows (wave w -> keys w*16..+15), B = Q regs
        bf16x8 ak;
        for (int j = 0; j < 8; ++j) ak[j] = (__bf16)0.0f;
        if (quad < 2)
            ak = *reinterpret_cast<const bf16x8*>(
                &k_buf[cur][(w * 16 + l15) * 16 + quad * 8]);
#pragma unroll
        for (int ni = 0; ni < 4; ++ni) {
            f32x4 s;
            for (int r = 0; r < 4; ++r) s[r] = 0.f;
            s = MFMA(ak, aq[ni], s);           // D[m=key][n=q]
            S4 u;
            u.b[0] = (__bf16)__expf(s[0]); u.b[1] = (__bf16)__expf(s[1]);
            u.b[2] = (__bf16)__expf(s[2]); u.b[3] = (__bf16)__expf(s[3]);
            *reinterpret_cast<short4*>(
                &p_lds[(oS * 64 + ni * 16 + l15) * 8 + sub]) = u.sh;
        }

        // barrier_B: P visible; DOES NOT drain vmcnt -> kt+1 DMA stays in flight
        asm volatile("s_waitcnt lgkmcnt(0)" ::: "memory");
        __builtin_amdgcn_s_barrier();
        asm volatile("" ::: "memory");
        __builtin_amdgcn_sched_barrier(0);

        // ---- PV phase: wave w owns ch-tiles {2w, 2w+1}
        const int chl = l15 & 7;
#pragma unroll
        for (int ks = 0; ks < 2; ++ks) {
            int pz = ((ks * 4 + quad) ^ chl);
            bf16x8 a0 = *reinterpret_cast<const bf16x8*>(
                &v_buf[cur][(((2 * w)     * 2 + (l15 >> 3)) * 64 + chl * 8 + pz) * 8]);
            bf16x8 a1 = *reinterpret_cast<const bf16x8*>(
                &v_buf[cur][(((2 * w + 1) * 2 + (l15 >> 3)) * 64 + chl * 8 + pz) * 8]);
            const int ob = (ks * 4 + quad) * 64;
            bf16x8 p0 = *reinterpret_cast<const bf16x8*>(&p_lds[(ob +  0 + l15) * 8]);
            bf16x8 p1 = *reinterpret_cast<const bf16x8*>(&p_lds[(ob + 16 + l15) * 8]);
            bf16x8 p2 = *reinterpret_cast<const bf16x8*>(&p_lds[(ob + 32 + l15) * 8]);
            bf16x8 p3 = *reinterpret_cast<const bf16x8*>(&p_lds[(ob + 48 + l15) * 8]);
            acc[0][0] = MFMA(a0, p0, acc[0][0]);
            acc[0][1] = MFMA(a0, p1, acc[0][1]);
            acc[0][2] = MFMA(a0, p2, acc[0][2]);
            acc[0][3] = MFMA(a0, p3, acc[0][3]);
            acc[1][0] = MFMA(a1, p0, acc[1][0]);
            acc[1][1] = MFMA(a1, p1, acc[1][1]);
            acc[1][2] = MFMA(a1, p2, acc[1][2]);
            acc[1][3] = MFMA(a1, p3, acc[1][3]);
            // l-sum: wave w reduces its own q-group (balanced across waves)
            bf16x8 pw = *reinterpret_cast<const bf16x8*>(&p_lds[(ob + w * 16 + l15) * 8]);
            lacc = MFMA(ones, pw, lacc);
        }
    }

    // write av partials: av_part[sp][n][c] fp32
    float* dst = av_part + (size_t)sp * 1024000;
    for (int mi = 0; mi < 2; ++mi)
        for (int ni = 0; ni < 4; ++ni) {
            int n  = n0q + ni * 16 + l15;
            int ch = (2 * w + mi) * 16 + quad * 4;
            *reinterpret_cast<f32x4*>(&dst[n * 128 + ch]) = acc[mi][ni];
        }
    if (quad == 0)
        l_part[sp * N_POS + n0q + w * 16 + l15] = lacc[0];
}

// ---------------------------------------------------------------------------
// Kernel C: split-K reduce + normalize fused with y = wa @ av + ba (MFMA) +
// BN stats.  grid 250, block 512 (8 waves).
// v7: 512 threads -> 2 waves/SIMD.  The av_part gather (5 splits x float4x2
// per octet) is the measured latency hole (tile-16 variant: 57 us, VALUBusy
// 1.9%); grid is pinned at 250 so waves/SIMD is the only occupancy lever.
// Each thread builds exactly ONE c-octet; each wave owns ONE mtile (8x16=128).
// ---------------------------------------------------------------------------
__global__ __launch_bounds__(512) void proj_out_kernel(
    const float* __restrict__ av_part, const float* __restrict__ l_part,
    const float* __restrict__ wa, const float* __restrict__ ba,
    float* __restrict__ y_ws, float* __restrict__ bn_sum, float* __restrict__ bn_sumsq)
{
    __shared__ __bf16 b_lds[4096];   // 32n x 128c fragment-packed, swizzled

    const int t    = threadIdx.x;
    const int n0   = blockIdx.x * 32;
    const int lane = t & 63;
    const int w    = t >> 6;         // 0..7
    const int l15  = lane & 15;
    const int quad = lane >> 4;

    // build normalized B tile: 512 c-octets, 1 per thread (coalesced reads)
    {
        int n = t >> 4, oc = t & 15;
        float l = 0.f;
#pragma unroll
        for (int s = 0; s < KSPLIT; ++s) l += l_part[s * N_POS + n0 + n];
        float4 a0 = make_float4(0.f, 0.f, 0.f, 0.f);
        float4 a1 = make_float4(0.f, 0.f, 0.f, 0.f);
#pragma unroll
        for (int s = 0; s < KSPLIT; ++s) {
            const float* p = av_part + (size_t)s * 1024000 + (n0 + n) * 128 + oc * 8;
            float4 u = *reinterpret_cast<const float4*>(p);
            float4 v = *reinterpret_cast<const float4*>(p + 4);
            a0.x += u.x; a0.y += u.y; a0.z += u.z; a0.w += u.w;
            a1.x += v.x; a1.y += v.y; a1.z += v.z; a1.w += v.w;
        }
        float inv = 1.f / l;
        union { int4 iv; __bf16 b[8]; } u;
        u.b[0]=(__bf16)(a0.x*inv); u.b[1]=(__bf16)(a0.y*inv);
        u.b[2]=(__bf16)(a0.z*inv); u.b[3]=(__bf16)(a0.w*inv);
        u.b[4]=(__bf16)(a1.x*inv); u.b[5]=(__bf16)(a1.y*inv);
        u.b[6]=(__bf16)(a1.z*inv); u.b[7]=(__bf16)(a1.w*inv);
        int A = (n >> 4) * 16 + oc;
        int slot = (n & 15) ^ (oc & 7);
        *reinterpret_cast<int4*>(&b_lds[(A * 16 + slot) * 8]) = u.iv;
    }

    // A-frags: wa rows for mtile w
    bf16x8 aw[4];
    f32x4  acc[2];
    {
        const float* wrow = wa + (w * 16 + l15) * 128;
        for (int ks = 0; ks < 4; ++ks) {
            float4 f0 = *reinterpret_cast<const float4*>(wrow + ks * 32 + quad * 8);
            float4 f1 = *reinterpret_cast<const float4*>(wrow + ks * 32 + quad * 8 + 4);
            bf16x8 a;
            a[0]=(__bf16)f0.x; a[1]=(__bf16)f0.y; a[2]=(__bf16)f0.z; a[3]=(__bf16)f0.w;
            a[4]=(__bf16)f1.x; a[5]=(__bf16)f1.y; a[6]=(__bf16)f1.z; a[7]=(__bf16)f1.w;
            aw[ks] = a;
        }
        for (int ni = 0; ni < 2; ++ni) {
            acc[ni][0] = ba[w * 16 + quad * 4 + 0];
            acc[ni][1] = ba[w * 16 + quad * 4 + 1];
            acc[ni][2] = ba[w * 16 + quad * 4 + 2];
            acc[ni][3] = ba[w * 16 + quad * 4 + 3];
        }
    }
    __syncthreads();

    for (int ks = 0; ks < 4; ++ks) {
        int oc = ks * 4 + quad;
        int slot = l15 ^ (oc & 7);
        bf16x8 b0 = *reinterpret_cast<const bf16x8*>(&b_lds[((0  + oc) * 16 + slot) * 8]);
        bf16x8 b1 = *reinterpret_cast<const bf16x8*>(&b_lds[((16 + oc) * 16 + slot) * 8]);
        acc[0] = MFMA(aw[ks], b0, acc[0]);
        acc[1] = MFMA(aw[ks], b1, acc[1]);
    }

    // y writes [c][n] + BN partial stats
    for (int r = 0; r < 4; ++r) {
        int ch = w * 16 + quad * 4 + r;
        float v0 = acc[0][r];
        float v1 = acc[1][r];
        y_ws[ch * N_POS + n0 + 0  + l15] = v0;
        y_ws[ch * N_POS + n0 + 16 + l15] = v1;
        float s1 = v0 + v1;
        float s2 = v0 * v0 + v1 * v1;
#pragma unroll
        for (int off = 8; off >= 1; off >>= 1) {
            s1 += __shfl_xor(s1, off, 64);
            s2 += __shfl_xor(s2, off, 64);
        }
        if (l15 == 0) {
            atomicAdd(&bn_sum[ch],   s1);
            atomicAdd(&bn_sumsq[ch], s2);
        }
    }
}

// ---------------------------------------------------------------------------
// Kernel D: BatchNorm (training stats) + ReLU + residual. grid 1000, block 256.
// ---------------------------------------------------------------------------
__global__ __launch_bounds__(256) void bn_relu_kernel(
    const float* __restrict__ y_ws, const float* __restrict__ x,
    const float* __restrict__ bn_sum, const float* __restrict__ bn_sumsq,
    const float* __restrict__ bn_w, const float* __restrict__ bn_b,
    float* __restrict__ out)
{
    const int i4 = blockIdx.x * 256 + threadIdx.x;
    const int c  = i4 / 2000;
    const float mean  = bn_sum[c]   * (1.f / 8000.f);
    const float var   = bn_sumsq[c] * (1.f / 8000.f) - mean * mean;
    const float rstd  = rsqrtf(var + 1e-5f);
    const float scale = bn_w[c] * rstd;
    const float shift = bn_b[c] - mean * scale;

    float4 y4 = reinterpret_cast<const float4*>(y_ws)[i4];
    float4 x4 = reinterpret_cast<const float4*>(x)[i4];
    float4 o4;
    o4.x = fmaxf(y4.x * scale + shift, 0.f) + x4.x;
    o4.y = fmaxf(y4.y * scale + shift, 0.f) + x4.y;
    o4.z = fmaxf(y4.z * scale + shift, 0.f) + x4.z;
    o4.w = fmaxf(y4.w * scale + shift, 0.f) + x4.w;
    reinterpret_cast<float4*>(out)[i4] = o4;
}

// ---------------------------------------------------------------------------
extern "C" void kernel_launch(void* const* d_in, const int* in_sizes, int n_in,
                              void* d_out, int out_size, void* d_ws, size_t ws_size,
                              hipStream_t stream)
{
    const float* x    = (const float*)d_in[0];
    const float* wq   = (const float*)d_in[1];
    const float* bq   = (const float*)d_in[2];
    const float* wk   = (const float*)d_in[3];
    const float* bk   = (const float*)d_in[4];
    const float* wv   = (const float*)d_in[5];
    const float* bv   = (const float*)d_in[6];
    const float* wa   = (const float*)d_in[7];
    const float* ba   = (const float*)d_in[8];
    const float* bn_w = (const float*)d_in[9];
    const float* bn_b = (const float*)d_in[10];
    float* out = (float*)d_out;

    char* base = (char*)d_ws;
    // byte layout (~27.3 MB):
    float*  av_part = (float*)base;                    // 20,480,000 B (5 x 8000 x 128 f32)
    __bf16* q_bf    = (__bf16*)(base + 20480000);      //    256,000 B
    __bf16* k_bf    = (__bf16*)(base + 20736000);      //    256,000 B
    __bf16* v_bf    = (__bf16*)(base + 20992000);      //  2,048,000 B
    float*  l_part  = (float*)(base + 23040000);       //    160,000 B
    float*  bn_sum   = (float*)(base + 23200000);      //        512 B
    float*  bn_sumsq = bn_sum + 128;                   //        512 B
    float*  y_ws    = (float*)(base + 23201024);       //  4,096,000 B

    hipMemsetAsync(bn_sum, 0, 1024, stream);
    qkv_kernel<<<250, 512, 0, stream>>>(x, wq, bq, wk, bk, wv, bv, q_bf, k_bf, v_bf);
    attn_kernel<<<QTILES * KSPLIT, 256, 0, stream>>>(q_bf, k_bf, v_bf, av_part, l_part);
    proj_out_kernel<<<250, 512, 0, stream>>>(av_part, l_part, wa, ba, y_ws, bn_sum, bn_sumsq);
    bn_relu_kernel<<<1000, 256, 0, stream>>>(y_ws, x, bn_sum, bn_sumsq, bn_w, bn_b, out);
}

// Round 9
// 160.932 us; speedup vs baseline: 1.5073x; 1.3315x over previous
//
#include <hip/hip_runtime.h>
#include <math.h>

#define N_POS 8000
#define C_CH  128
#define KSPLIT 5
#define KT_PER 25      // 125 k-tiles of 64 keys, 25 per split
#define QTILES 125     // q-tiles of 64 queries

typedef __bf16 bf16x8 __attribute__((ext_vector_type(8)));
typedef float  f32x4  __attribute__((ext_vector_type(4)));

#define MFMA(a,b,c) __builtin_amdgcn_mfma_f32_16x16x32_bf16((a),(b),(c),0,0,0)

// MFMA 16x16x32 lane layouts (verified m89/m120):
//   A[m][k]: m = lane&15, k = (lane>>4)*8 + j
//   B[k][n]: n = lane&15, k = (lane>>4)*8 + j
//   D[m][n]: n = lane&15, m = (lane>>4)*4 + reg

#define GLOAD_LDS(gp, lp) \
    __builtin_amdgcn_global_load_lds( \
        (const __attribute__((address_space(1))) void*)(gp), \
        (__attribute__((address_space(3))) void*)(lp), 16, 0, 0)

// ---------------------------------------------------------------------------
// Kernel W: one-time weight repack fp32 -> fragment-ordered bf16.
// Chunk g = (mtg*4 + ks)*64 + lane holds A-frag bf16x8 for (mtile,ks,lane):
//   value[j] = W[mtg_row(l15)][ks*32 + quad*8 + j].
// mtg 0..9 = stacked {wq, wk, wv(8 tiles)}; mtg 10..17 = wa (8 tiles).
// 4608 chunks total = 73728 B.  Consumers read 16 B/lane COALESCED --
// removes the 16-rows-x-512B-stride scattered loads every block was doing
// (round-8 diagnosis: qkv 72.7 us at 0.9% HBM / 0.17% MFMA).
// ---------------------------------------------------------------------------
__global__ __launch_bounds__(256) void wcvt_kernel(
    const float* __restrict__ wq, const float* __restrict__ wk,
    const float* __restrict__ wv, const float* __restrict__ wa,
    __bf16* __restrict__ w_frag)
{
    const int g = blockIdx.x * 256 + threadIdx.x;   // 0..4607
    if (g >= 4608) return;
    const int mtg  = g >> 8;          // 0..17
    const int ks   = (g >> 6) & 3;
    const int lane = g & 63;
    const int l15  = lane & 15;
    const int quad = lane >> 4;

    const float* wrow;
    if (mtg == 0)       wrow = wq + l15 * 128;
    else if (mtg == 1)  wrow = wk + l15 * 128;
    else if (mtg < 10)  wrow = wv + ((mtg - 2) * 16 + l15) * 128;
    else                wrow = wa + ((mtg - 10) * 16 + l15) * 128;

    float4 f0 = *reinterpret_cast<const float4*>(wrow + ks * 32 + quad * 8);
    float4 f1 = *reinterpret_cast<const float4*>(wrow + ks * 32 + quad * 8 + 4);
    union { int4 iv; __bf16 b[8]; } u;
    u.b[0]=(__bf16)f0.x; u.b[1]=(__bf16)f0.y; u.b[2]=(__bf16)f0.z; u.b[3]=(__bf16)f0.w;
    u.b[4]=(__bf16)f1.x; u.b[5]=(__bf16)f1.y; u.b[6]=(__bf16)f1.z; u.b[7]=(__bf16)f1.w;
    *reinterpret_cast<int4*>(&w_frag[(size_t)g * 8]) = u.iv;
}

// ---------------------------------------------------------------------------
// Kernel A: QKV projections via MFMA. grid 250 (n-tiles of 32), block 256.
// Round-1 structure; v8: A-frags from w_frag (coalesced 16B/lane, L2-hot)
// instead of per-block scattered fp32 row loads; x loads issued 4-deep
// before conversion.
// out rows: o 0..15 -> q, 16..31 -> k, 32..159 -> v(ch=o-32)
// ---------------------------------------------------------------------------
__global__ __launch_bounds__(256) void qkv_kernel(
    const float* __restrict__ x, const __bf16* __restrict__ w_frag,
    const float* __restrict__ bq, const float* __restrict__ bk,
    const float* __restrict__ bv,
    __bf16* __restrict__ q_bf, __bf16* __restrict__ k_bf, __bf16* __restrict__ v_bf)
{
    __shared__ __bf16 x_lds[32 * 136];          // [n][c]
    __shared__ __bf16 v_out[128 * 36];          // [ch][n]

    const int t    = threadIdx.x;
    const int n0   = blockIdx.x * 32;
    const int lane = t & 63;
    const int w    = t >> 6;
    const int l15  = lane & 15;
    const int quad = lane >> 4;

    // stage x tile [128c x 32n] -> x_lds[n][c] bf16; 4 loads in flight first
    float4 xv[4];
#pragma unroll
    for (int r = 0; r < 4; ++r) {
        int f = r * 256 + t;
        int ch = f >> 3, n4 = f & 7;
        xv[r] = *reinterpret_cast<const float4*>(&x[ch * N_POS + n0 + n4 * 4]);
    }
#pragma unroll
    for (int r = 0; r < 4; ++r) {
        int f = r * 256 + t;
        int ch = f >> 3, n4 = f & 7;
        x_lds[(n4 * 4 + 0) * 136 + ch] = (__bf16)xv[r].x;
        x_lds[(n4 * 4 + 1) * 136 + ch] = (__bf16)xv[r].y;
        x_lds[(n4 * 4 + 2) * 136 + ch] = (__bf16)xv[r].z;
        x_lds[(n4 * 4 + 3) * 136 + ch] = (__bf16)xv[r].w;
    }

    // A-frags: coalesced from w_frag. wave w owns mtiles {w, w+4, w+8<10}
    bf16x8 aw[3][4];
    f32x4  acc[3][2];
    const int nmt = (w < 2) ? 3 : 2;
    for (int mi = 0; mi < nmt; ++mi) {
        int mt = w + 4 * mi;
        for (int ks = 0; ks < 4; ++ks)
            aw[mi][ks] = *reinterpret_cast<const bf16x8*>(
                &w_frag[(size_t)((mt * 4 + ks) * 64 + lane) * 8]);
        const float* brow;
        if (mt == 0)      brow = bq;
        else if (mt == 1) brow = bk;
        else              brow = bv + (mt - 2) * 16;
        for (int ni = 0; ni < 2; ++ni) {
            acc[mi][ni][0] = brow[quad * 4 + 0]; acc[mi][ni][1] = brow[quad * 4 + 1];
            acc[mi][ni][2] = brow[quad * 4 + 2]; acc[mi][ni][3] = brow[quad * 4 + 3];
        }
    }
    __syncthreads();

    for (int ks = 0; ks < 4; ++ks) {
        bf16x8 b0 = *reinterpret_cast<const bf16x8*>(&x_lds[(0  + l15) * 136 + ks * 32 + quad * 8]);
        bf16x8 b1 = *reinterpret_cast<const bf16x8*>(&x_lds[(16 + l15) * 136 + ks * 32 + quad * 8]);
        for (int mi = 0; mi < nmt; ++mi) {
            acc[mi][0] = MFMA(aw[mi][ks], b0, acc[mi][0]);
            acc[mi][1] = MFMA(aw[mi][ks], b1, acc[mi][1]);
        }
    }

    union S4 { short4 s; __bf16 b[4]; };
    for (int mi = 0; mi < nmt; ++mi) {
        int mt = w + 4 * mi;
        for (int ni = 0; ni < 2; ++ni) {
            S4 u;
            u.b[0]=(__bf16)acc[mi][ni][0]; u.b[1]=(__bf16)acc[mi][ni][1];
            u.b[2]=(__bf16)acc[mi][ni][2]; u.b[3]=(__bf16)acc[mi][ni][3];
            int n = n0 + ni * 16 + l15;
            if (mt == 0) {
                *reinterpret_cast<short4*>(&q_bf[n * 16 + quad * 4]) = u.s;
            } else if (mt == 1) {
                *reinterpret_cast<short4*>(&k_bf[n * 16 + quad * 4]) = u.s;
            } else {
                int ch0 = (mt - 2) * 16 + quad * 4;
                int nl  = ni * 16 + l15;
                v_out[(ch0 + 0) * 36 + nl] = u.b[0];
                v_out[(ch0 + 1) * 36 + nl] = u.b[1];
                v_out[(ch0 + 2) * 36 + nl] = u.b[2];
                v_out[(ch0 + 3) * 36 + nl] = u.b[3];
            }
        }
    }
    __syncthreads();
    for (int r = 0; r < 4; ++r) {
        int f = r * 256 + t;
        int ch = f >> 3, n4 = f & 7;
        int2 d = *reinterpret_cast<const int2*>(&v_out[ch * 36 + n4 * 4]);
        *reinterpret_cast<int2*>(&v_bf[ch * N_POS + n0 + n4 * 4]) = d;
    }
}

// ---------------------------------------------------------------------------
// Kernel B: fused attention, split-K, MFMA, global_load_lds double-buffer.
// (round-1 version, best measured ~39 us; later variants neutral or worse.)
// ---------------------------------------------------------------------------
__global__ __launch_bounds__(256, 3) void attn_kernel(
    const __bf16* __restrict__ q_bf, const __bf16* __restrict__ k_bf,
    const __bf16* __restrict__ v_bf, float* __restrict__ av_part,
    float* __restrict__ l_part)
{
    __shared__ __bf16 v_buf[2][8192];   // 16 KB each
    __shared__ __bf16 k_buf[2][1024];   // 2 KB each
    __shared__ __bf16 p_lds[4096];      // 8 KB; total 45056 B -> 3 blocks/CU

    const int t    = threadIdx.x;
    const int qt   = blockIdx.x % QTILES;
    const int sp   = blockIdx.x / QTILES;
    const int n0q  = qt * 64;
    const int lane = t & 63;
    const int w    = t >> 6;
    const int l15  = lane & 15;
    const int quad = lane >> 4;

    // staging maps (per lane, loop-invariant)
    const int chL   = lane >> 3;              // V: low 3 bits of channel
    const int vpart = (lane & 7) ^ chL;       // V: key-octet (XOR swizzle)
    const int kkey  = lane >> 1;              // K: key within 32-key half
    const int khalf = lane & 1;               // K: dim half

    // Q B-frags in registers (k-dim 16 padded to 32 with zeros), 4 q-groups
    bf16x8 aq[4];
    for (int ni = 0; ni < 4; ++ni) {
        for (int j = 0; j < 8; ++j) aq[ni][j] = (__bf16)0.0f;
        if (quad < 2)
            aq[ni] = *reinterpret_cast<const bf16x8*>(
                &q_bf[(n0q + ni * 16 + l15) * 16 + quad * 8]);
    }
    bf16x8 ones;
    for (int j = 0; j < 8; ++j) ones[j] = (__bf16)1.0f;

    f32x4 acc[2][4];
    for (int mi = 0; mi < 2; ++mi)
        for (int ni = 0; ni < 4; ++ni)
            for (int r = 0; r < 4; ++r) acc[mi][ni][r] = 0.f;
    f32x4 lacc;
    for (int r = 0; r < 4; ++r) lacc[r] = 0.f;

    const int kt0 = sp * KT_PER;

    // issue one tile's staging DMA: 4 V ops per wave; K ops on waves 0,1 only
    auto stage = [&](int kt, int buf) {
        const int n0k = kt * 64;
        for (int r = 0; r < 4; ++r) {
            int R = w * 4 + r;   // wave-uniform LDS base
            GLOAD_LDS(v_bf + (8 * R + chL) * N_POS + n0k + vpart * 8,
                      &v_buf[buf][R * 512]);
        }
        if (w < 2)
            GLOAD_LDS(k_bf + (size_t)(n0k + w * 32 + kkey) * 16 + khalf * 8,
                      &k_buf[buf][w * 512]);
    };

    stage(kt0, 0);

    const int oS  = w * 2 + (quad >> 1);   // P-write octet
    const int sub = (quad & 1) * 4;        // P-write elem offset in chunk

    union S4 { short4 sh; __bf16 b[4]; };

    for (int kt = kt0; kt < kt0 + KT_PER; ++kt) {
        const int cur = (kt - kt0) & 1;
        __syncthreads();   // barrier_A: vmcnt(0) drain of tile-kt DMA (1 iter of cover)

        // issue next tile's DMA NOW -> in flight across S + barrier_B + PV
        if (kt + 1 < kt0 + KT_PER) stage(kt + 1, cur ^ 1);

        // ---- S phase: A = K rows (wave w -> keys w*16..+15), B = Q regs
        bf16x8 ak;
        for (int j = 0; j < 8; ++j) ak[j] = (__bf16)0.0f;
        if (quad < 2)
            ak = *reinterpret_cast<const bf16x8*>(
                &k_buf[cur][(w * 16 + l15) * 16 + quad * 8]);
#pragma unroll
        for (int ni = 0; ni < 4; ++ni) {
            f32x4 s;
            for (int r = 0; r < 4; ++r) s[r] = 0.f;
            s = MFMA(ak, aq[ni], s);           // D[m=key][n=q]
            S4 u;
            u.b[0] = (__bf16)__expf(s[0]); u.b[1] = (__bf16)__expf(s[1]);
            u.b[2] = (__bf16)__expf(s[2]); u.b[3] = (__bf16)__expf(s[3]);
            *reinterpret_cast<short4*>(
                &p_lds[(oS * 64 + ni * 16 + l15) * 8 + sub]) = u.sh;
        }

        // barrier_B: P visible; DOES NOT drain vmcnt -> kt+1 DMA stays in flight
        asm volatile("s_waitcnt lgkmcnt(0)" ::: "memory");
        __builtin_amdgcn_s_barrier();
        asm volatile("" ::: "memory");
        __builtin_amdgcn_sched_barrier(0);

        // ---- PV phase: wave w owns ch-tiles {2w, 2w+1}
        const int chl = l15 & 7;
#pragma unroll
        for (int ks = 0; ks < 2; ++ks) {
            int pz = ((ks * 4 + quad) ^ chl);
            bf16x8 a0 = *reinterpret_cast<const bf16x8*>(
                &v_buf[cur][(((2 * w)     * 2 + (l15 >> 3)) * 64 + chl * 8 + pz) * 8]);
            bf16x8 a1 = *reinterpret_cast<const bf16x8*>(
                &v_buf[cur][(((2 * w + 1) * 2 + (l15 >> 3)) * 64 + chl * 8 + pz) * 8]);
            const int ob = (ks * 4 + quad) * 64;
            bf16x8 p0 = *reinterpret_cast<const bf16x8*>(&p_lds[(ob +  0 + l15) * 8]);
            bf16x8 p1 = *reinterpret_cast<const bf16x8*>(&p_lds[(ob + 16 + l15) * 8]);
            bf16x8 p2 = *reinterpret_cast<const bf16x8*>(&p_lds[(ob + 32 + l15) * 8]);
            bf16x8 p3 = *reinterpret_cast<const bf16x8*>(&p_lds[(ob + 48 + l15) * 8]);
            acc[0][0] = MFMA(a0, p0, acc[0][0]);
            acc[0][1] = MFMA(a0, p1, acc[0][1]);
            acc[0][2] = MFMA(a0, p2, acc[0][2]);
            acc[0][3] = MFMA(a0, p3, acc[0][3]);
            acc[1][0] = MFMA(a1, p0, acc[1][0]);
            acc[1][1] = MFMA(a1, p1, acc[1][1]);
            acc[1][2] = MFMA(a1, p2, acc[1][2]);
            acc[1][3] = MFMA(a1, p3, acc[1][3]);
            // l-sum: wave w reduces its own q-group (balanced across waves)
            bf16x8 pw = *reinterpret_cast<const bf16x8*>(&p_lds[(ob + w * 16 + l15) * 8]);
            lacc = MFMA(ones, pw, lacc);
        }
    }

    // write av partials: av_part[sp][n][c] fp32
    float* dst = av_part + (size_t)sp * 1024000;
    for (int mi = 0; mi < 2; ++mi)
        for (int ni = 0; ni < 4; ++ni) {
            int n  = n0q + ni * 16 + l15;
            int ch = (2 * w + mi) * 16 + quad * 4;
            *reinterpret_cast<f32x4*>(&dst[n * 128 + ch]) = acc[mi][ni];
        }
    if (quad == 0)
        l_part[sp * N_POS + n0q + w * 16 + l15] = lacc[0];
}

// ---------------------------------------------------------------------------
// Kernel C: split-K reduce + normalize fused with y = wa @ av + ba (MFMA) +
// BN stats.  grid 250, n-tile 32, block 256 (round-1 fused version).
// v8: wa A-frags from w_frag (coalesced) instead of scattered fp32 rows.
// ---------------------------------------------------------------------------
__global__ __launch_bounds__(256) void proj_out_kernel(
    const float* __restrict__ av_part, const float* __restrict__ l_part,
    const __bf16* __restrict__ wa_frag, const float* __restrict__ ba,
    float* __restrict__ y_ws, float* __restrict__ bn_sum, float* __restrict__ bn_sumsq)
{
    __shared__ __bf16 b_lds[4096];   // 32n x 128c fragment-packed, swizzled

    const int t    = threadIdx.x;
    const int n0   = blockIdx.x * 32;
    const int lane = t & 63;
    const int w    = t >> 6;
    const int l15  = lane & 15;
    const int quad = lane >> 4;

    // build normalized B tile: 512 c-octets, 2 per thread (coalesced reads)
    for (int r = 0; r < 2; ++r) {
        int g = r * 256 + t;
        int n = g >> 4, oc = g & 15;
        float l = 0.f;
#pragma unroll
        for (int s = 0; s < KSPLIT; ++s) l += l_part[s * N_POS + n0 + n];
        float4 a0 = make_float4(0.f, 0.f, 0.f, 0.f);
        float4 a1 = make_float4(0.f, 0.f, 0.f, 0.f);
#pragma unroll
        for (int s = 0; s < KSPLIT; ++s) {
            const float* p = av_part + (size_t)s * 1024000 + (n0 + n) * 128 + oc * 8;
            float4 u = *reinterpret_cast<const float4*>(p);
            float4 v = *reinterpret_cast<const float4*>(p + 4);
            a0.x += u.x; a0.y += u.y; a0.z += u.z; a0.w += u.w;
            a1.x += v.x; a1.y += v.y; a1.z += v.z; a1.w += v.w;
        }
        float inv = 1.f / l;
        union { int4 iv; __bf16 b[8]; } u;
        u.b[0]=(__bf16)(a0.x*inv); u.b[1]=(__bf16)(a0.y*inv);
        u.b[2]=(__bf16)(a0.z*inv); u.b[3]=(__bf16)(a0.w*inv);
        u.b[4]=(__bf16)(a1.x*inv); u.b[5]=(__bf16)(a1.y*inv);
        u.b[6]=(__bf16)(a1.z*inv); u.b[7]=(__bf16)(a1.w*inv);
        int A = (n >> 4) * 16 + oc;
        int slot = (n & 15) ^ (oc & 7);
        *reinterpret_cast<int4*>(&b_lds[(A * 16 + slot) * 8]) = u.iv;
    }

    // A-frags: wa mtiles {2w, 2w+1} from fragment-packed buffer (coalesced)
    bf16x8 aw[2][4];
    f32x4  acc[2][2];
    for (int mi = 0; mi < 2; ++mi) {
        int mt = 2 * w + mi;
        for (int ks = 0; ks < 4; ++ks)
            aw[mi][ks] = *reinterpret_cast<const bf16x8*>(
                &wa_frag[(size_t)((mt * 4 + ks) * 64 + lane) * 8]);
        for (int ni = 0; ni < 2; ++ni) {
            acc[mi][ni][0] = ba[mt * 16 + quad * 4 + 0];
            acc[mi][ni][1] = ba[mt * 16 + quad * 4 + 1];
            acc[mi][ni][2] = ba[mt * 16 + quad * 4 + 2];
            acc[mi][ni][3] = ba[mt * 16 + quad * 4 + 3];
        }
    }
    __syncthreads();

    for (int ks = 0; ks < 4; ++ks) {
        int oc = ks * 4 + quad;
        int slot = l15 ^ (oc & 7);
        bf16x8 b0 = *reinterpret_cast<const bf16x8*>(&b_lds[((0  + oc) * 16 + slot) * 8]);
        bf16x8 b1 = *reinterpret_cast<const bf16x8*>(&b_lds[((16 + oc) * 16 + slot) * 8]);
        for (int mi = 0; mi < 2; ++mi) {
            acc[mi][0] = MFMA(aw[mi][ks], b0, acc[mi][0]);
            acc[mi][1] = MFMA(aw[mi][ks], b1, acc[mi][1]);
        }
    }

    // y writes [c][n] + BN partial stats
    for (int mi = 0; mi < 2; ++mi) {
        for (int r = 0; r < 4; ++r) {
            int ch = (2 * w + mi) * 16 + quad * 4 + r;
            float v0 = acc[mi][0][r];
            float v1 = acc[mi][1][r];
            y_ws[ch * N_POS + n0 + 0  + l15] = v0;
            y_ws[ch * N_POS + n0 + 16 + l15] = v1;
            float s1 = v0 + v1;
            float s2 = v0 * v0 + v1 * v1;
#pragma unroll
            for (int off = 8; off >= 1; off >>= 1) {
                s1 += __shfl_xor(s1, off, 64);
                s2 += __shfl_xor(s2, off, 64);
            }
            if (l15 == 0) {
                atomicAdd(&bn_sum[ch],   s1);
                atomicAdd(&bn_sumsq[ch], s2);
            }
        }
    }
}

// ---------------------------------------------------------------------------
// Kernel D: BatchNorm (training stats) + ReLU + residual. grid 1000, block 256.
// ---------------------------------------------------------------------------
__global__ __launch_bounds__(256) void bn_relu_kernel(
    const float* __restrict__ y_ws, const float* __restrict__ x,
    const float* __restrict__ bn_sum, const float* __restrict__ bn_sumsq,
    const float* __restrict__ bn_w, const float* __restrict__ bn_b,
    float* __restrict__ out)
{
    const int i4 = blockIdx.x * 256 + threadIdx.x;
    const int c  = i4 / 2000;
    const float mean  = bn_sum[c]   * (1.f / 8000.f);
    const float var   = bn_sumsq[c] * (1.f / 8000.f) - mean * mean;
    const float rstd  = rsqrtf(var + 1e-5f);
    const float scale = bn_w[c] * rstd;
    const float shift = bn_b[c] - mean * scale;

    float4 y4 = reinterpret_cast<const float4*>(y_ws)[i4];
    float4 x4 = reinterpret_cast<const float4*>(x)[i4];
    float4 o4;
    o4.x = fmaxf(y4.x * scale + shift, 0.f) + x4.x;
    o4.y = fmaxf(y4.y * scale + shift, 0.f) + x4.y;
    o4.z = fmaxf(y4.z * scale + shift, 0.f) + x4.z;
    o4.w = fmaxf(y4.w * scale + shift, 0.f) + x4.w;
    reinterpret_cast<float4*>(out)[i4] = o4;
}

// ---------------------------------------------------------------------------
extern "C" void kernel_launch(void* const* d_in, const int* in_sizes, int n_in,
                              void* d_out, int out_size, void* d_ws, size_t ws_size,
                              hipStream_t stream)
{
    const float* x    = (const float*)d_in[0];
    const float* wq   = (const float*)d_in[1];
    const float* bq   = (const float*)d_in[2];
    const float* wk   = (const float*)d_in[3];
    const float* bk   = (const float*)d_in[4];
    const float* wv   = (const float*)d_in[5];
    const float* bv   = (const float*)d_in[6];
    const float* wa   = (const float*)d_in[7];
    const float* ba   = (const float*)d_in[8];
    const float* bn_w = (const float*)d_in[9];
    const float* bn_b = (const float*)d_in[10];
    float* out = (float*)d_out;

    char* base = (char*)d_ws;
    // byte layout (~27.4 MB):
    float*  av_part = (float*)base;                    // 20,480,000 B (5 x 8000 x 128 f32)
    __bf16* q_bf    = (__bf16*)(base + 20480000);      //    256,000 B
    __bf16* k_bf    = (__bf16*)(base + 20736000);      //    256,000 B
    __bf16* v_bf    = (__bf16*)(base + 20992000);      //  2,048,000 B
    float*  l_part  = (float*)(base + 23040000);       //    160,000 B
    float*  bn_sum   = (float*)(base + 23200000);      //        512 B
    float*  bn_sumsq = bn_sum + 128;                   //        512 B
    float*  y_ws    = (float*)(base + 23201024);       //  4,096,000 B
    __bf16* w_frag  = (__bf16*)(base + 27297024);      //     73,728 B (4608 chunks)
    __bf16* wa_frag = w_frag + 2560 * 8;               //  (chunks 2560..4607)

    hipMemsetAsync(bn_sum, 0, 1024, stream);
    wcvt_kernel<<<18, 256, 0, stream>>>(wq, wk, wv, wa, w_frag);
    qkv_kernel<<<250, 256, 0, stream>>>(x, w_frag, bq, bk, bv, q_bf, k_bf, v_bf);
    attn_kernel<<<QTILES * KSPLIT, 256, 0, stream>>>(q_bf, k_bf, v_bf, av_part, l_part);
    proj_out_kernel<<<250, 256, 0, stream>>>(av_part, l_part, wa_frag, ba, y_ws, bn_sum, bn_sumsq);
    bn_relu_kernel<<<1000, 256, 0, stream>>>(y_ws, x, bn_sum, bn_sumsq, bn_w, bn_b, out);
}

// Round 10
// 157.368 us; speedup vs baseline: 1.5415x; 1.0226x over previous
//
#include <hip/hip_runtime.h>
#include <math.h>

#define N_POS 8000
#define C_CH  128
#define KSPLIT 5
#define KT_PER 25      // 125 k-tiles of 64 keys, 25 per split
#define QTILES 125     // q-tiles of 64 queries

typedef __bf16 bf16x8 __attribute__((ext_vector_type(8)));
typedef float  f32x4  __attribute__((ext_vector_type(4)));

#define MFMA(a,b,c) __builtin_amdgcn_mfma_f32_16x16x32_bf16((a),(b),(c),0,0,0)

// MFMA 16x16x32 lane layouts (verified m89/m120):
//   A[m][k]: m = lane&15, k = (lane>>4)*8 + j
//   B[k][n]: n = lane&15, k = (lane>>4)*8 + j
//   D[m][n]: n = lane&15, m = (lane>>4)*4 + reg

#define GLOAD_LDS(gp, lp) \
    __builtin_amdgcn_global_load_lds( \
        (const __attribute__((address_space(1))) void*)(gp), \
        (__attribute__((address_space(3))) void*)(lp), 16, 0, 0)

// ---------------------------------------------------------------------------
// Kernel W: one-time weight repack fp32 -> fragment-ordered bf16.
// Chunk g = (mtg*4 + ks)*64 + lane holds A-frag bf16x8 for (mtile,ks,lane).
// mtg 0..9 = stacked {wq, wk, wv(8 tiles)}; mtg 10..17 = wa (8 tiles).
// ---------------------------------------------------------------------------
__global__ __launch_bounds__(256) void wcvt_kernel(
    const float* __restrict__ wq, const float* __restrict__ wk,
    const float* __restrict__ wv, const float* __restrict__ wa,
    __bf16* __restrict__ w_frag)
{
    const int g = blockIdx.x * 256 + threadIdx.x;   // 0..4607
    if (g >= 4608) return;
    const int mtg  = g >> 8;          // 0..17
    const int ks   = (g >> 6) & 3;
    const int lane = g & 63;
    const int l15  = lane & 15;
    const int quad = lane >> 4;

    const float* wrow;
    if (mtg == 0)       wrow = wq + l15 * 128;
    else if (mtg == 1)  wrow = wk + l15 * 128;
    else if (mtg < 10)  wrow = wv + ((mtg - 2) * 16 + l15) * 128;
    else                wrow = wa + ((mtg - 10) * 16 + l15) * 128;

    float4 f0 = *reinterpret_cast<const float4*>(wrow + ks * 32 + quad * 8);
    float4 f1 = *reinterpret_cast<const float4*>(wrow + ks * 32 + quad * 8 + 4);
    union { int4 iv; __bf16 b[8]; } u;
    u.b[0]=(__bf16)f0.x; u.b[1]=(__bf16)f0.y; u.b[2]=(__bf16)f0.z; u.b[3]=(__bf16)f0.w;
    u.b[4]=(__bf16)f1.x; u.b[5]=(__bf16)f1.y; u.b[6]=(__bf16)f1.z; u.b[7]=(__bf16)f1.w;
    *reinterpret_cast<int4*>(&w_frag[(size_t)g * 8]) = u.iv;
}

// ---------------------------------------------------------------------------
// Kernel A: QKV projections via MFMA. grid 250 (n-tiles of 32), block 256.
// (round-9 version: w_frag coalesced A-frags + 4-deep x load ILP.)
// out rows: o 0..15 -> q, 16..31 -> k, 32..159 -> v(ch=o-32)
// ---------------------------------------------------------------------------
__global__ __launch_bounds__(256) void qkv_kernel(
    const float* __restrict__ x, const __bf16* __restrict__ w_frag,
    const float* __restrict__ bq, const float* __restrict__ bk,
    const float* __restrict__ bv,
    __bf16* __restrict__ q_bf, __bf16* __restrict__ k_bf, __bf16* __restrict__ v_bf)
{
    __shared__ __bf16 x_lds[32 * 136];          // [n][c]
    __shared__ __bf16 v_out[128 * 36];          // [ch][n]

    const int t    = threadIdx.x;
    const int n0   = blockIdx.x * 32;
    const int lane = t & 63;
    const int w    = t >> 6;
    const int l15  = lane & 15;
    const int quad = lane >> 4;

    // stage x tile [128c x 32n] -> x_lds[n][c] bf16; 4 loads in flight first
    float4 xv[4];
#pragma unroll
    for (int r = 0; r < 4; ++r) {
        int f = r * 256 + t;
        int ch = f >> 3, n4 = f & 7;
        xv[r] = *reinterpret_cast<const float4*>(&x[ch * N_POS + n0 + n4 * 4]);
    }
#pragma unroll
    for (int r = 0; r < 4; ++r) {
        int f = r * 256 + t;
        int ch = f >> 3, n4 = f & 7;
        x_lds[(n4 * 4 + 0) * 136 + ch] = (__bf16)xv[r].x;
        x_lds[(n4 * 4 + 1) * 136 + ch] = (__bf16)xv[r].y;
        x_lds[(n4 * 4 + 2) * 136 + ch] = (__bf16)xv[r].z;
        x_lds[(n4 * 4 + 3) * 136 + ch] = (__bf16)xv[r].w;
    }

    // A-frags: coalesced from w_frag. wave w owns mtiles {w, w+4, w+8<10}
    bf16x8 aw[3][4];
    f32x4  acc[3][2];
    const int nmt = (w < 2) ? 3 : 2;
    for (int mi = 0; mi < nmt; ++mi) {
        int mt = w + 4 * mi;
        for (int ks = 0; ks < 4; ++ks)
            aw[mi][ks] = *reinterpret_cast<const bf16x8*>(
                &w_frag[(size_t)((mt * 4 + ks) * 64 + lane) * 8]);
        const float* brow;
        if (mt == 0)      brow = bq;
        else if (mt == 1) brow = bk;
        else              brow = bv + (mt - 2) * 16;
        for (int ni = 0; ni < 2; ++ni) {
            acc[mi][ni][0] = brow[quad * 4 + 0]; acc[mi][ni][1] = brow[quad * 4 + 1];
            acc[mi][ni][2] = brow[quad * 4 + 2]; acc[mi][ni][3] = brow[quad * 4 + 3];
        }
    }
    __syncthreads();

    for (int ks = 0; ks < 4; ++ks) {
        bf16x8 b0 = *reinterpret_cast<const bf16x8*>(&x_lds[(0  + l15) * 136 + ks * 32 + quad * 8]);
        bf16x8 b1 = *reinterpret_cast<const bf16x8*>(&x_lds[(16 + l15) * 136 + ks * 32 + quad * 8]);
        for (int mi = 0; mi < nmt; ++mi) {
            acc[mi][0] = MFMA(aw[mi][ks], b0, acc[mi][0]);
            acc[mi][1] = MFMA(aw[mi][ks], b1, acc[mi][1]);
        }
    }

    union S4 { short4 s; __bf16 b[4]; };
    for (int mi = 0; mi < nmt; ++mi) {
        int mt = w + 4 * mi;
        for (int ni = 0; ni < 2; ++ni) {
            S4 u;
            u.b[0]=(__bf16)acc[mi][ni][0]; u.b[1]=(__bf16)acc[mi][ni][1];
            u.b[2]=(__bf16)acc[mi][ni][2]; u.b[3]=(__bf16)acc[mi][ni][3];
            int n = n0 + ni * 16 + l15;
            if (mt == 0) {
                *reinterpret_cast<short4*>(&q_bf[n * 16 + quad * 4]) = u.s;
            } else if (mt == 1) {
                *reinterpret_cast<short4*>(&k_bf[n * 16 + quad * 4]) = u.s;
            } else {
                int ch0 = (mt - 2) * 16 + quad * 4;
                int nl  = ni * 16 + l15;
                v_out[(ch0 + 0) * 36 + nl] = u.b[0];
                v_out[(ch0 + 1) * 36 + nl] = u.b[1];
                v_out[(ch0 + 2) * 36 + nl] = u.b[2];
                v_out[(ch0 + 3) * 36 + nl] = u.b[3];
            }
        }
    }
    __syncthreads();
    for (int r = 0; r < 4; ++r) {
        int f = r * 256 + t;
        int ch = f >> 3, n4 = f & 7;
        int2 d = *reinterpret_cast<const int2*>(&v_out[ch * 36 + n4 * 4]);
        *reinterpret_cast<int2*>(&v_bf[ch * N_POS + n0 + n4 * 4]) = d;
    }
}

// ---------------------------------------------------------------------------
// Kernel B: fused attention, split-K, MFMA, global_load_lds double-buffer.
// (round-1 core, ~39 us.)  v10: av partials stored BF16 -- they are
// normalized by 1/sum(l) immediately after the reduce, so fp32 precision on
// the partials is wasted; halves attn's write traffic (20.2 -> ~10 MB, the
// majority of its HBM bytes) and halves proj's reduce-load chain.
// ---------------------------------------------------------------------------
__global__ __launch_bounds__(256, 3) void attn_kernel(
    const __bf16* __restrict__ q_bf, const __bf16* __restrict__ k_bf,
    const __bf16* __restrict__ v_bf, __bf16* __restrict__ av_part,
    float* __restrict__ l_part)
{
    __shared__ __bf16 v_buf[2][8192];   // 16 KB each
    __shared__ __bf16 k_buf[2][1024];   // 2 KB each
    __shared__ __bf16 p_lds[4096];      // 8 KB; total 45056 B -> 3 blocks/CU

    const int t    = threadIdx.x;
    const int qt   = blockIdx.x % QTILES;
    const int sp   = blockIdx.x / QTILES;
    const int n0q  = qt * 64;
    const int lane = t & 63;
    const int w    = t >> 6;
    const int l15  = lane & 15;
    const int quad = lane >> 4;

    // staging maps (per lane, loop-invariant)
    const int chL   = lane >> 3;              // V: low 3 bits of channel
    const int vpart = (lane & 7) ^ chL;       // V: key-octet (XOR swizzle)
    const int kkey  = lane >> 1;              // K: key within 32-key half
    const int khalf = lane & 1;               // K: dim half

    // Q B-frags in registers (k-dim 16 padded to 32 with zeros), 4 q-groups
    bf16x8 aq[4];
    for (int ni = 0; ni < 4; ++ni) {
        for (int j = 0; j < 8; ++j) aq[ni][j] = (__bf16)0.0f;
        if (quad < 2)
            aq[ni] = *reinterpret_cast<const bf16x8*>(
                &q_bf[(n0q + ni * 16 + l15) * 16 + quad * 8]);
    }
    bf16x8 ones;
    for (int j = 0; j < 8; ++j) ones[j] = (__bf16)1.0f;

    f32x4 acc[2][4];
    for (int mi = 0; mi < 2; ++mi)
        for (int ni = 0; ni < 4; ++ni)
            for (int r = 0; r < 4; ++r) acc[mi][ni][r] = 0.f;
    f32x4 lacc;
    for (int r = 0; r < 4; ++r) lacc[r] = 0.f;

    const int kt0 = sp * KT_PER;

    // issue one tile's staging DMA: 4 V ops per wave; K ops on waves 0,1 only
    auto stage = [&](int kt, int buf) {
        const int n0k = kt * 64;
        for (int r = 0; r < 4; ++r) {
            int R = w * 4 + r;   // wave-uniform LDS base
            GLOAD_LDS(v_bf + (8 * R + chL) * N_POS + n0k + vpart * 8,
                      &v_buf[buf][R * 512]);
        }
        if (w < 2)
            GLOAD_LDS(k_bf + (size_t)(n0k + w * 32 + kkey) * 16 + khalf * 8,
                      &k_buf[buf][w * 512]);
    };

    stage(kt0, 0);

    const int oS  = w * 2 + (quad >> 1);   // P-write octet
    const int sub = (quad & 1) * 4;        // P-write elem offset in chunk

    union S4 { short4 sh; __bf16 b[4]; };

    for (int kt = kt0; kt < kt0 + KT_PER; ++kt) {
        const int cur = (kt - kt0) & 1;
        __syncthreads();   // barrier_A: vmcnt(0) drain of tile-kt DMA (1 iter of cover)

        // issue next tile's DMA NOW -> in flight across S + barrier_B + PV
        if (kt + 1 < kt0 + KT_PER) stage(kt + 1, cur ^ 1);

        // ---- S phase: A = K rows (wave w -> keys w*16..+15), B = Q regs
        bf16x8 ak;
        for (int j = 0; j < 8; ++j) ak[j] = (__bf16)0.0f;
        if (quad < 2)
            ak = *reinterpret_cast<const bf16x8*>(
                &k_buf[cur][(w * 16 + l15) * 16 + quad * 8]);
#pragma unroll
        for (int ni = 0; ni < 4; ++ni) {
            f32x4 s;
            for (int r = 0; r < 4; ++r) s[r] = 0.f;
            s = MFMA(ak, aq[ni], s);           // D[m=key][n=q]
            S4 u;
            u.b[0] = (__bf16)__expf(s[0]); u.b[1] = (__bf16)__expf(s[1]);
            u.b[2] = (__bf16)__expf(s[2]); u.b[3] = (__bf16)__expf(s[3]);
            *reinterpret_cast<short4*>(
                &p_lds[(oS * 64 + ni * 16 + l15) * 8 + sub]) = u.sh;
        }

        // barrier_B: P visible; DOES NOT drain vmcnt -> kt+1 DMA stays in flight
        asm volatile("s_waitcnt lgkmcnt(0)" ::: "memory");
        __builtin_amdgcn_s_barrier();
        asm volatile("" ::: "memory");
        __builtin_amdgcn_sched_barrier(0);

        // ---- PV phase: wave w owns ch-tiles {2w, 2w+1}
        const int chl = l15 & 7;
#pragma unroll
        for (int ks = 0; ks < 2; ++ks) {
            int pz = ((ks * 4 + quad) ^ chl);
            bf16x8 a0 = *reinterpret_cast<const bf16x8*>(
                &v_buf[cur][(((2 * w)     * 2 + (l15 >> 3)) * 64 + chl * 8 + pz) * 8]);
            bf16x8 a1 = *reinterpret_cast<const bf16x8*>(
                &v_buf[cur][(((2 * w + 1) * 2 + (l15 >> 3)) * 64 + chl * 8 + pz) * 8]);
            const int ob = (ks * 4 + quad) * 64;
            bf16x8 p0 = *reinterpret_cast<const bf16x8*>(&p_lds[(ob +  0 + l15) * 8]);
            bf16x8 p1 = *reinterpret_cast<const bf16x8*>(&p_lds[(ob + 16 + l15) * 8]);
            bf16x8 p2 = *reinterpret_cast<const bf16x8*>(&p_lds[(ob + 32 + l15) * 8]);
            bf16x8 p3 = *reinterpret_cast<const bf16x8*>(&p_lds[(ob + 48 + l15) * 8]);
            acc[0][0] = MFMA(a0, p0, acc[0][0]);
            acc[0][1] = MFMA(a0, p1, acc[0][1]);
            acc[0][2] = MFMA(a0, p2, acc[0][2]);
            acc[0][3] = MFMA(a0, p3, acc[0][3]);
            acc[1][0] = MFMA(a1, p0, acc[1][0]);
            acc[1][1] = MFMA(a1, p1, acc[1][1]);
            acc[1][2] = MFMA(a1, p2, acc[1][2]);
            acc[1][3] = MFMA(a1, p3, acc[1][3]);
            // l-sum: wave w reduces its own q-group (balanced across waves)
            bf16x8 pw = *reinterpret_cast<const bf16x8*>(&p_lds[(ob + w * 16 + l15) * 8]);
            lacc = MFMA(ones, pw, lacc);
        }
    }

    // write av partials BF16: av_part[sp][n][c]
    __bf16* dst = av_part + (size_t)sp * 1024000;
    union S4b { short4 sh; __bf16 b[4]; };
    for (int mi = 0; mi < 2; ++mi)
        for (int ni = 0; ni < 4; ++ni) {
            int n  = n0q + ni * 16 + l15;
            int ch = (2 * w + mi) * 16 + quad * 4;
            S4b u;
            u.b[0] = (__bf16)acc[mi][ni][0];
            u.b[1] = (__bf16)acc[mi][ni][1];
            u.b[2] = (__bf16)acc[mi][ni][2];
            u.b[3] = (__bf16)acc[mi][ni][3];
            *reinterpret_cast<short4*>(&dst[n * 128 + ch]) = u.sh;
        }
    if (quad == 0)
        l_part[sp * N_POS + n0q + w * 16 + l15] = lacc[0];
}

// ---------------------------------------------------------------------------
// Kernel C: split-K reduce (bf16 partials) + normalize fused with
// y = wa @ av + ba (MFMA) + BN stats.  grid 250, n-tile 32, block 256.
// v10: reduce reads one int4 (8 bf16 ch) per split -- load chain 20+5 -> 10+5.
// ---------------------------------------------------------------------------
__global__ __launch_bounds__(256) void proj_out_kernel(
    const __bf16* __restrict__ av_part, const float* __restrict__ l_part,
    const __bf16* __restrict__ wa_frag, const float* __restrict__ ba,
    float* __restrict__ y_ws, float* __restrict__ bn_sum, float* __restrict__ bn_sumsq)
{
    __shared__ __bf16 b_lds[4096];   // 32n x 128c fragment-packed, swizzled

    const int t    = threadIdx.x;
    const int n0   = blockIdx.x * 32;
    const int lane = t & 63;
    const int w    = t >> 6;
    const int l15  = lane & 15;
    const int quad = lane >> 4;

    // build normalized B tile: 512 c-octets, 2 per thread (coalesced reads)
    for (int r = 0; r < 2; ++r) {
        int g = r * 256 + t;
        int n = g >> 4, oc = g & 15;
        float l = 0.f;
#pragma unroll
        for (int s = 0; s < KSPLIT; ++s) l += l_part[s * N_POS + n0 + n];
        // gather the 5 bf16 octets first (independent loads), then unpack
        union B8 { int4 iv; __bf16 b[8]; } raw[KSPLIT];
#pragma unroll
        for (int s = 0; s < KSPLIT; ++s)
            raw[s].iv = *reinterpret_cast<const int4*>(
                av_part + (size_t)s * 1024000 + (n0 + n) * 128 + oc * 8);
        float a[8];
#pragma unroll
        for (int j = 0; j < 8; ++j) a[j] = 0.f;
#pragma unroll
        for (int s = 0; s < KSPLIT; ++s)
#pragma unroll
            for (int j = 0; j < 8; ++j) a[j] += (float)raw[s].b[j];
        float inv = 1.f / l;
        union { int4 iv; __bf16 b[8]; } u;
#pragma unroll
        for (int j = 0; j < 8; ++j) u.b[j] = (__bf16)(a[j] * inv);
        int A = (n >> 4) * 16 + oc;
        int slot = (n & 15) ^ (oc & 7);
        *reinterpret_cast<int4*>(&b_lds[(A * 16 + slot) * 8]) = u.iv;
    }

    // A-frags: wa mtiles {2w, 2w+1} from fragment-packed buffer (coalesced)
    bf16x8 aw[2][4];
    f32x4  acc[2][2];
    for (int mi = 0; mi < 2; ++mi) {
        int mt = 2 * w + mi;
        for (int ks = 0; ks < 4; ++ks)
            aw[mi][ks] = *reinterpret_cast<const bf16x8*>(
                &wa_frag[(size_t)((mt * 4 + ks) * 64 + lane) * 8]);
        for (int ni = 0; ni < 2; ++ni) {
            acc[mi][ni][0] = ba[mt * 16 + quad * 4 + 0];
            acc[mi][ni][1] = ba[mt * 16 + quad * 4 + 1];
            acc[mi][ni][2] = ba[mt * 16 + quad * 4 + 2];
            acc[mi][ni][3] = ba[mt * 16 + quad * 4 + 3];
        }
    }
    __syncthreads();

    for (int ks = 0; ks < 4; ++ks) {
        int oc = ks * 4 + quad;
        int slot = l15 ^ (oc & 7);
        bf16x8 b0 = *reinterpret_cast<const bf16x8*>(&b_lds[((0  + oc) * 16 + slot) * 8]);
        bf16x8 b1 = *reinterpret_cast<const bf16x8*>(&b_lds[((16 + oc) * 16 + slot) * 8]);
        for (int mi = 0; mi < 2; ++mi) {
            acc[mi][0] = MFMA(aw[mi][ks], b0, acc[mi][0]);
            acc[mi][1] = MFMA(aw[mi][ks], b1, acc[mi][1]);
        }
    }

    // y writes [c][n] + BN partial stats
    for (int mi = 0; mi < 2; ++mi) {
        for (int r = 0; r < 4; ++r) {
            int ch = (2 * w + mi) * 16 + quad * 4 + r;
            float v0 = acc[mi][0][r];
            float v1 = acc[mi][1][r];
            y_ws[ch * N_POS + n0 + 0  + l15] = v0;
            y_ws[ch * N_POS + n0 + 16 + l15] = v1;
            float s1 = v0 + v1;
            float s2 = v0 * v0 + v1 * v1;
#pragma unroll
            for (int off = 8; off >= 1; off >>= 1) {
                s1 += __shfl_xor(s1, off, 64);
                s2 += __shfl_xor(s2, off, 64);
            }
            if (l15 == 0) {
                atomicAdd(&bn_sum[ch],   s1);
                atomicAdd(&bn_sumsq[ch], s2);
            }
        }
    }
}

// ---------------------------------------------------------------------------
// Kernel D: BatchNorm (training stats) + ReLU + residual. grid 1000, block 256.
// ---------------------------------------------------------------------------
__global__ __launch_bounds__(256) void bn_relu_kernel(
    const float* __restrict__ y_ws, const float* __restrict__ x,
    const float* __restrict__ bn_sum, const float* __restrict__ bn_sumsq,
    const float* __restrict__ bn_w, const float* __restrict__ bn_b,
    float* __restrict__ out)
{
    const int i4 = blockIdx.x * 256 + threadIdx.x;
    const int c  = i4 / 2000;
    const float mean  = bn_sum[c]   * (1.f / 8000.f);
    const float var   = bn_sumsq[c] * (1.f / 8000.f) - mean * mean;
    const float rstd  = rsqrtf(var + 1e-5f);
    const float scale = bn_w[c] * rstd;
    const float shift = bn_b[c] - mean * scale;

    float4 y4 = reinterpret_cast<const float4*>(y_ws)[i4];
    float4 x4 = reinterpret_cast<const float4*>(x)[i4];
    float4 o4;
    o4.x = fmaxf(y4.x * scale + shift, 0.f) + x4.x;
    o4.y = fmaxf(y4.y * scale + shift, 0.f) + x4.y;
    o4.z = fmaxf(y4.z * scale + shift, 0.f) + x4.z;
    o4.w = fmaxf(y4.w * scale + shift, 0.f) + x4.w;
    reinterpret_cast<float4*>(out)[i4] = o4;
}

// ---------------------------------------------------------------------------
extern "C" void kernel_launch(void* const* d_in, const int* in_sizes, int n_in,
                              void* d_out, int out_size, void* d_ws, size_t ws_size,
                              hipStream_t stream)
{
    const float* x    = (const float*)d_in[0];
    const float* wq   = (const float*)d_in[1];
    const float* bq   = (const float*)d_in[2];
    const float* wk   = (const float*)d_in[3];
    const float* bk   = (const float*)d_in[4];
    const float* wv   = (const float*)d_in[5];
    const float* bv   = (const float*)d_in[6];
    const float* wa   = (const float*)d_in[7];
    const float* ba   = (const float*)d_in[8];
    const float* bn_w = (const float*)d_in[9];
    const float* bn_b = (const float*)d_in[10];
    float* out = (float*)d_out;

    char* base = (char*)d_ws;
    // byte layout (~17.1 MB):
    __bf16* av_part = (__bf16*)base;                   // 10,240,000 B (5 x 8000 x 128 bf16)
    __bf16* q_bf    = (__bf16*)(base + 10240000);      //    256,000 B
    __bf16* k_bf    = (__bf16*)(base + 10496000);      //    256,000 B
    __bf16* v_bf    = (__bf16*)(base + 10752000);      //  2,048,000 B
    float*  l_part  = (float*)(base + 12800000);       //    160,000 B
    float*  bn_sum   = (float*)(base + 12960000);      //        512 B
    float*  bn_sumsq = bn_sum + 128;                   //        512 B
    float*  y_ws    = (float*)(base + 12961024);       //  4,096,000 B
    __bf16* w_frag  = (__bf16*)(base + 17057024);      //     73,728 B (4608 chunks)
    __bf16* wa_frag = w_frag + 2560 * 8;               //  (chunks 2560..4607)

    hipMemsetAsync(bn_sum, 0, 1024, stream);
    wcvt_kernel<<<18, 256, 0, stream>>>(wq, wk, wv, wa, w_frag);
    qkv_kernel<<<250, 256, 0, stream>>>(x, w_frag, bq, bk, bv, q_bf, k_bf, v_bf);
    attn_kernel<<<QTILES * KSPLIT, 256, 0, stream>>>(q_bf, k_bf, v_bf, av_part, l_part);
    proj_out_kernel<<<250, 256, 0, stream>>>(av_part, l_part, wa_frag, ba, y_ws, bn_sum, bn_sumsq);
    bn_relu_kernel<<<1000, 256, 0, stream>>>(y_ws, x, bn_sum, bn_sumsq, bn_w, bn_b, out);
}

// Round 12
// 155.605 us; speedup vs baseline: 1.5589x; 1.0113x over previous
//
#include <hip/hip_runtime.h>
#include <math.h>

#define N_POS 8000
#define C_CH  128
#define KSPLIT 5
#define KT_PER 25      // 125 k-tiles of 64 keys, 25 per split
#define QTILES 125     // q-tiles of 64 queries

typedef __bf16 bf16x8 __attribute__((ext_vector_type(8)));
typedef float  f32x4  __attribute__((ext_vector_type(4)));

#define MFMA(a,b,c) __builtin_amdgcn_mfma_f32_16x16x32_bf16((a),(b),(c),0,0,0)

// MFMA 16x16x32 lane layouts (verified m89/m120):
//   A[m][k]: m = lane&15, k = (lane>>4)*8 + j
//   B[k][n]: n = lane&15, k = (lane>>4)*8 + j
//   D[m][n]: n = lane&15, m = (lane>>4)*4 + reg

#define GLOAD_LDS(gp, lp) \
    __builtin_amdgcn_global_load_lds( \
        (const __attribute__((address_space(1))) void*)(gp), \
        (__attribute__((address_space(3))) void*)(lp), 16, 0, 0)

// ---------------------------------------------------------------------------
// Kernel W: one-time weight repack fp32 -> fragment-ordered bf16, and
// (block 0) zeroing of bn_sum/bn_sumsq (folds the memset dispatch away).
// Chunk g = (mtg*4 + ks)*64 + lane holds A-frag bf16x8 for (mtile,ks,lane).
// mtg 0..9 = stacked {wq, wk, wv(8 tiles)}; mtg 10..17 = wa (8 tiles).
// ---------------------------------------------------------------------------
__global__ __launch_bounds__(256) void wcvt_kernel(
    const float* __restrict__ wq, const float* __restrict__ wk,
    const float* __restrict__ wv, const float* __restrict__ wa,
    __bf16* __restrict__ w_frag, float* __restrict__ bn_clear)
{
    if (blockIdx.x == 0) bn_clear[threadIdx.x] = 0.f;   // 256 floats = sum+sumsq

    const int g = blockIdx.x * 256 + threadIdx.x;   // 0..4607
    if (g >= 4608) return;
    const int mtg  = g >> 8;          // 0..17
    const int ks   = (g >> 6) & 3;
    const int lane = g & 63;
    const int l15  = lane & 15;
    const int quad = lane >> 4;

    const float* wrow;
    if (mtg == 0)       wrow = wq + l15 * 128;
    else if (mtg == 1)  wrow = wk + l15 * 128;
    else if (mtg < 10)  wrow = wv + ((mtg - 2) * 16 + l15) * 128;
    else                wrow = wa + ((mtg - 10) * 16 + l15) * 128;

    float4 f0 = *reinterpret_cast<const float4*>(wrow + ks * 32 + quad * 8);
    float4 f1 = *reinterpret_cast<const float4*>(wrow + ks * 32 + quad * 8 + 4);
    union { int4 iv; __bf16 b[8]; } u;
    u.b[0]=(__bf16)f0.x; u.b[1]=(__bf16)f0.y; u.b[2]=(__bf16)f0.z; u.b[3]=(__bf16)f0.w;
    u.b[4]=(__bf16)f1.x; u.b[5]=(__bf16)f1.y; u.b[6]=(__bf16)f1.z; u.b[7]=(__bf16)f1.w;
    *reinterpret_cast<int4*>(&w_frag[(size_t)g * 8]) = u.iv;
}

// ---------------------------------------------------------------------------
// Kernel A: QKV projections via MFMA. grid 250 (n-tiles of 32), block 256.
// (round-9 version: w_frag coalesced A-frags + 4-deep x load ILP.)
// out rows: o 0..15 -> q, 16..31 -> k, 32..159 -> v(ch=o-32)
// ---------------------------------------------------------------------------
__global__ __launch_bounds__(256) void qkv_kernel(
    const float* __restrict__ x, const __bf16* __restrict__ w_frag,
    const float* __restrict__ bq, const float* __restrict__ bk,
    const float* __restrict__ bv,
    __bf16* __restrict__ q_bf, __bf16* __restrict__ k_bf, __bf16* __restrict__ v_bf)
{
    __shared__ __bf16 x_lds[32 * 136];          // [n][c]
    __shared__ __bf16 v_out[128 * 36];          // [ch][n]

    const int t    = threadIdx.x;
    const int n0   = blockIdx.x * 32;
    const int lane = t & 63;
    const int w    = t >> 6;
    const int l15  = lane & 15;
    const int quad = lane >> 4;

    // stage x tile [128c x 32n] -> x_lds[n][c] bf16; 4 loads in flight first
    float4 xv[4];
#pragma unroll
    for (int r = 0; r < 4; ++r) {
        int f = r * 256 + t;
        int ch = f >> 3, n4 = f & 7;
        xv[r] = *reinterpret_cast<const float4*>(&x[ch * N_POS + n0 + n4 * 4]);
    }
#pragma unroll
    for (int r = 0; r < 4; ++r) {
        int f = r * 256 + t;
        int ch = f >> 3, n4 = f & 7;
        x_lds[(n4 * 4 + 0) * 136 + ch] = (__bf16)xv[r].x;
        x_lds[(n4 * 4 + 1) * 136 + ch] = (__bf16)xv[r].y;
        x_lds[(n4 * 4 + 2) * 136 + ch] = (__bf16)xv[r].z;
        x_lds[(n4 * 4 + 3) * 136 + ch] = (__bf16)xv[r].w;
    }

    // A-frags: coalesced from w_frag. wave w owns mtiles {w, w+4, w+8<10}
    bf16x8 aw[3][4];
    f32x4  acc[3][2];
    const int nmt = (w < 2) ? 3 : 2;
    for (int mi = 0; mi < nmt; ++mi) {
        int mt = w + 4 * mi;
        for (int ks = 0; ks < 4; ++ks)
            aw[mi][ks] = *reinterpret_cast<const bf16x8*>(
                &w_frag[(size_t)((mt * 4 + ks) * 64 + lane) * 8]);
        const float* brow;
        if (mt == 0)      brow = bq;
        else if (mt == 1) brow = bk;
        else              brow = bv + (mt - 2) * 16;
        for (int ni = 0; ni < 2; ++ni) {
            acc[mi][ni][0] = brow[quad * 4 + 0]; acc[mi][ni][1] = brow[quad * 4 + 1];
            acc[mi][ni][2] = brow[quad * 4 + 2]; acc[mi][ni][3] = brow[quad * 4 + 3];
        }
    }
    __syncthreads();

    for (int ks = 0; ks < 4; ++ks) {
        bf16x8 b0 = *reinterpret_cast<const bf16x8*>(&x_lds[(0  + l15) * 136 + ks * 32 + quad * 8]);
        bf16x8 b1 = *reinterpret_cast<const bf16x8*>(&x_lds[(16 + l15) * 136 + ks * 32 + quad * 8]);
        for (int mi = 0; mi < nmt; ++mi) {
            acc[mi][0] = MFMA(aw[mi][ks], b0, acc[mi][0]);
            acc[mi][1] = MFMA(aw[mi][ks], b1, acc[mi][1]);
        }
    }

    union S4 { short4 s; __bf16 b[4]; };
    for (int mi = 0; mi < nmt; ++mi) {
        int mt = w + 4 * mi;
        for (int ni = 0; ni < 2; ++ni) {
            S4 u;
            u.b[0]=(__bf16)acc[mi][ni][0]; u.b[1]=(__bf16)acc[mi][ni][1];
            u.b[2]=(__bf16)acc[mi][ni][2]; u.b[3]=(__bf16)acc[mi][ni][3];
            int n = n0 + ni * 16 + l15;
            if (mt == 0) {
                *reinterpret_cast<short4*>(&q_bf[n * 16 + quad * 4]) = u.s;
            } else if (mt == 1) {
                *reinterpret_cast<short4*>(&k_bf[n * 16 + quad * 4]) = u.s;
            } else {
                int ch0 = (mt - 2) * 16 + quad * 4;
                int nl  = ni * 16 + l15;
                v_out[(ch0 + 0) * 36 + nl] = u.b[0];
                v_out[(ch0 + 1) * 36 + nl] = u.b[1];
                v_out[(ch0 + 2) * 36 + nl] = u.b[2];
                v_out[(ch0 + 3) * 36 + nl] = u.b[3];
            }
        }
    }
    __syncthreads();
    for (int r = 0; r < 4; ++r) {
        int f = r * 256 + t;
        int ch = f >> 3, n4 = f & 7;
        int2 d = *reinterpret_cast<const int2*>(&v_out[ch * 36 + n4 * 4]);
        *reinterpret_cast<int2*>(&v_bf[ch * N_POS + n0 + n4 * 4]) = d;
    }
}

// ---------------------------------------------------------------------------
// Kernel B: fused attention, split-K, MFMA, global_load_lds double-buffer.
// (round-10 version: round-1 core + bf16 av partials, ~37 us.)
// ---------------------------------------------------------------------------
__global__ __launch_bounds__(256, 3) void attn_kernel(
    const __bf16* __restrict__ q_bf, const __bf16* __restrict__ k_bf,
    const __bf16* __restrict__ v_bf, __bf16* __restrict__ av_part,
    float* __restrict__ l_part)
{
    __shared__ __bf16 v_buf[2][8192];   // 16 KB each
    __shared__ __bf16 k_buf[2][1024];   // 2 KB each
    __shared__ __bf16 p_lds[4096];      // 8 KB; total 45056 B -> 3 blocks/CU

    const int t    = threadIdx.x;
    const int qt   = blockIdx.x % QTILES;
    const int sp   = blockIdx.x / QTILES;
    const int n0q  = qt * 64;
    const int lane = t & 63;
    const int w    = t >> 6;
    const int l15  = lane & 15;
    const int quad = lane >> 4;

    // staging maps (per lane, loop-invariant)
    const int chL   = lane >> 3;              // V: low 3 bits of channel
    const int vpart = (lane & 7) ^ chL;       // V: key-octet (XOR swizzle)
    const int kkey  = lane >> 1;              // K: key within 32-key half
    const int khalf = lane & 1;               // K: dim half

    // Q B-frags in registers (k-dim 16 padded to 32 with zeros), 4 q-groups
    bf16x8 aq[4];
    for (int ni = 0; ni < 4; ++ni) {
        for (int j = 0; j < 8; ++j) aq[ni][j] = (__bf16)0.0f;
        if (quad < 2)
            aq[ni] = *reinterpret_cast<const bf16x8*>(
                &q_bf[(n0q + ni * 16 + l15) * 16 + quad * 8]);
    }
    bf16x8 ones;
    for (int j = 0; j < 8; ++j) ones[j] = (__bf16)1.0f;

    f32x4 acc[2][4];
    for (int mi = 0; mi < 2; ++mi)
        for (int ni = 0; ni < 4; ++ni)
            for (int r = 0; r < 4; ++r) acc[mi][ni][r] = 0.f;
    f32x4 lacc;
    for (int r = 0; r < 4; ++r) lacc[r] = 0.f;

    const int kt0 = sp * KT_PER;

    // issue one tile's staging DMA: 4 V ops per wave; K ops on waves 0,1 only
    auto stage = [&](int kt, int buf) {
        const int n0k = kt * 64;
        for (int r = 0; r < 4; ++r) {
            int R = w * 4 + r;   // wave-uniform LDS base
            GLOAD_LDS(v_bf + (8 * R + chL) * N_POS + n0k + vpart * 8,
                      &v_buf[buf][R * 512]);
        }
        if (w < 2)
            GLOAD_LDS(k_bf + (size_t)(n0k + w * 32 + kkey) * 16 + khalf * 8,
                      &k_buf[buf][w * 512]);
    };

    stage(kt0, 0);

    const int oS  = w * 2 + (quad >> 1);   // P-write octet
    const int sub = (quad & 1) * 4;        // P-write elem offset in chunk

    union S4 { short4 sh; __bf16 b[4]; };

    for (int kt = kt0; kt < kt0 + KT_PER; ++kt) {
        const int cur = (kt - kt0) & 1;
        __syncthreads();   // barrier_A: vmcnt(0) drain of tile-kt DMA (1 iter of cover)

        // issue next tile's DMA NOW -> in flight across S + barrier_B + PV
        if (kt + 1 < kt0 + KT_PER) stage(kt + 1, cur ^ 1);

        // ---- S phase: A = K rows (wave w -> keys w*16..+15), B = Q regs
        bf16x8 ak;
        for (int j = 0; j < 8; ++j) ak[j] = (__bf16)0.0f;
        if (quad < 2)
            ak = *reinterpret_cast<const bf16x8*>(
                &k_buf[cur][(w * 16 + l15) * 16 + quad * 8]);
#pragma unroll
        for (int ni = 0; ni < 4; ++ni) {
            f32x4 s;
            for (int r = 0; r < 4; ++r) s[r] = 0.f;
            s = MFMA(ak, aq[ni], s);           // D[m=key][n=q]
            S4 u;
            u.b[0] = (__bf16)__expf(s[0]); u.b[1] = (__bf16)__expf(s[1]);
            u.b[2] = (__bf16)__expf(s[2]); u.b[3] = (__bf16)__expf(s[3]);
            *reinterpret_cast<short4*>(
                &p_lds[(oS * 64 + ni * 16 + l15) * 8 + sub]) = u.sh;
        }

        // barrier_B: P visible; DOES NOT drain vmcnt -> kt+1 DMA stays in flight
        asm volatile("s_waitcnt lgkmcnt(0)" ::: "memory");
        __builtin_amdgcn_s_barrier();
        asm volatile("" ::: "memory");
        __builtin_amdgcn_sched_barrier(0);

        // ---- PV phase: wave w owns ch-tiles {2w, 2w+1}
        const int chl = l15 & 7;
#pragma unroll
        for (int ks = 0; ks < 2; ++ks) {
            int pz = ((ks * 4 + quad) ^ chl);
            bf16x8 a0 = *reinterpret_cast<const bf16x8*>(
                &v_buf[cur][(((2 * w)     * 2 + (l15 >> 3)) * 64 + chl * 8 + pz) * 8]);
            bf16x8 a1 = *reinterpret_cast<const bf16x8*>(
                &v_buf[cur][(((2 * w + 1) * 2 + (l15 >> 3)) * 64 + chl * 8 + pz) * 8]);
            const int ob = (ks * 4 + quad) * 64;
            bf16x8 p0 = *reinterpret_cast<const bf16x8*>(&p_lds[(ob +  0 + l15) * 8]);
            bf16x8 p1 = *reinterpret_cast<const bf16x8*>(&p_lds[(ob + 16 + l15) * 8]);
            bf16x8 p2 = *reinterpret_cast<const bf16x8*>(&p_lds[(ob + 32 + l15) * 8]);
            bf16x8 p3 = *reinterpret_cast<const bf16x8*>(&p_lds[(ob + 48 + l15) * 8]);
            acc[0][0] = MFMA(a0, p0, acc[0][0]);
            acc[0][1] = MFMA(a0, p1, acc[0][1]);
            acc[0][2] = MFMA(a0, p2, acc[0][2]);
            acc[0][3] = MFMA(a0, p3, acc[0][3]);
            acc[1][0] = MFMA(a1, p0, acc[1][0]);
            acc[1][1] = MFMA(a1, p1, acc[1][1]);
            acc[1][2] = MFMA(a1, p2, acc[1][2]);
            acc[1][3] = MFMA(a1, p3, acc[1][3]);
            // l-sum: wave w reduces its own q-group (balanced across waves)
            bf16x8 pw = *reinterpret_cast<const bf16x8*>(&p_lds[(ob + w * 16 + l15) * 8]);
            lacc = MFMA(ones, pw, lacc);
        }
    }

    // write av partials BF16: av_part[sp][n][c]
    __bf16* dst = av_part + (size_t)sp * 1024000;
    union S4b { short4 sh; __bf16 b[4]; };
    for (int mi = 0; mi < 2; ++mi)
        for (int ni = 0; ni < 4; ++ni) {
            int n  = n0q + ni * 16 + l15;
            int ch = (2 * w + mi) * 16 + quad * 4;
            S4b u;
            u.b[0] = (__bf16)acc[mi][ni][0];
            u.b[1] = (__bf16)acc[mi][ni][1];
            u.b[2] = (__bf16)acc[mi][ni][2];
            u.b[3] = (__bf16)acc[mi][ni][3];
            *reinterpret_cast<short4*>(&dst[n * 128 + ch]) = u.sh;
        }
    if (quad == 0)
        l_part[sp * N_POS + n0q + w * 16 + l15] = lacc[0];
}

// ---------------------------------------------------------------------------
// Kernel C: split-K reduce (bf16 partials) + normalize fused with
// y = wa @ av + ba (MFMA) + BN stats.  grid 250, n-tile 32, block 256.
// v11: y stored BF16 (stats still accumulated fp32) -- halves the
// proj-write + bn-read round trip.
// ---------------------------------------------------------------------------
__global__ __launch_bounds__(256) void proj_out_kernel(
    const __bf16* __restrict__ av_part, const float* __restrict__ l_part,
    const __bf16* __restrict__ wa_frag, const float* __restrict__ ba,
    __bf16* __restrict__ y_bf, float* __restrict__ bn_sum, float* __restrict__ bn_sumsq)
{
    __shared__ __bf16 b_lds[4096];   // 32n x 128c fragment-packed, swizzled

    const int t    = threadIdx.x;
    const int n0   = blockIdx.x * 32;
    const int lane = t & 63;
    const int w    = t >> 6;
    const int l15  = lane & 15;
    const int quad = lane >> 4;

    // build normalized B tile: 512 c-octets, 2 per thread (coalesced reads)
    for (int r = 0; r < 2; ++r) {
        int g = r * 256 + t;
        int n = g >> 4, oc = g & 15;
        float l = 0.f;
#pragma unroll
        for (int s = 0; s < KSPLIT; ++s) l += l_part[s * N_POS + n0 + n];
        // gather the 5 bf16 octets first (independent loads), then unpack
        union B8 { int4 iv; __bf16 b[8]; } raw[KSPLIT];
#pragma unroll
        for (int s = 0; s < KSPLIT; ++s)
            raw[s].iv = *reinterpret_cast<const int4*>(
                av_part + (size_t)s * 1024000 + (n0 + n) * 128 + oc * 8);
        float a[8];
#pragma unroll
        for (int j = 0; j < 8; ++j) a[j] = 0.f;
#pragma unroll
        for (int s = 0; s < KSPLIT; ++s)
#pragma unroll
            for (int j = 0; j < 8; ++j) a[j] += (float)raw[s].b[j];
        float inv = 1.f / l;
        union { int4 iv; __bf16 b[8]; } u;
#pragma unroll
        for (int j = 0; j < 8; ++j) u.b[j] = (__bf16)(a[j] * inv);
        int A = (n >> 4) * 16 + oc;
        int slot = (n & 15) ^ (oc & 7);
        *reinterpret_cast<int4*>(&b_lds[(A * 16 + slot) * 8]) = u.iv;
    }

    // A-frags: wa mtiles {2w, 2w+1} from fragment-packed buffer (coalesced)
    bf16x8 aw[2][4];
    f32x4  acc[2][2];
    for (int mi = 0; mi < 2; ++mi) {
        int mt = 2 * w + mi;
        for (int ks = 0; ks < 4; ++ks)
            aw[mi][ks] = *reinterpret_cast<const bf16x8*>(
                &wa_frag[(size_t)((mt * 4 + ks) * 64 + lane) * 8]);
        for (int ni = 0; ni < 2; ++ni) {
            acc[mi][ni][0] = ba[mt * 16 + quad * 4 + 0];
            acc[mi][ni][1] = ba[mt * 16 + quad * 4 + 1];
            acc[mi][ni][2] = ba[mt * 16 + quad * 4 + 2];
            acc[mi][ni][3] = ba[mt * 16 + quad * 4 + 3];
        }
    }
    __syncthreads();

    for (int ks = 0; ks < 4; ++ks) {
        int oc = ks * 4 + quad;
        int slot = l15 ^ (oc & 7);
        bf16x8 b0 = *reinterpret_cast<const bf16x8*>(&b_lds[((0  + oc) * 16 + slot) * 8]);
        bf16x8 b1 = *reinterpret_cast<const bf16x8*>(&b_lds[((16 + oc) * 16 + slot) * 8]);
        for (int mi = 0; mi < 2; ++mi) {
            acc[mi][0] = MFMA(aw[mi][ks], b0, acc[mi][0]);
            acc[mi][1] = MFMA(aw[mi][ks], b1, acc[mi][1]);
        }
    }

    // y writes (bf16) [c][n] + BN partial stats (fp32)
    for (int mi = 0; mi < 2; ++mi) {
        for (int r = 0; r < 4; ++r) {
            int ch = (2 * w + mi) * 16 + quad * 4 + r;
            float v0 = acc[mi][0][r];
            float v1 = acc[mi][1][r];
            y_bf[ch * N_POS + n0 + 0  + l15] = (__bf16)v0;
            y_bf[ch * N_POS + n0 + 16 + l15] = (__bf16)v1;
            float s1 = v0 + v1;
            float s2 = v0 * v0 + v1 * v1;
#pragma unroll
            for (int off = 8; off >= 1; off >>= 1) {
                s1 += __shfl_xor(s1, off, 64);
                s2 += __shfl_xor(s2, off, 64);
            }
            if (l15 == 0) {
                atomicAdd(&bn_sum[ch],   s1);
                atomicAdd(&bn_sumsq[ch], s2);
            }
        }
    }
}

// ---------------------------------------------------------------------------
// Kernel D: BatchNorm (training stats) + ReLU + residual. grid 500, block 256.
// v11: y read as bf16 short8 (8 elems/thread).
// ---------------------------------------------------------------------------
__global__ __launch_bounds__(256) void bn_relu_kernel(
    const __bf16* __restrict__ y_bf, const float* __restrict__ x,
    const float* __restrict__ bn_sum, const float* __restrict__ bn_sumsq,
    const float* __restrict__ bn_w, const float* __restrict__ bn_b,
    float* __restrict__ out)
{
    const int i8 = blockIdx.x * 256 + threadIdx.x;   // 0..127999 (8 elems each)
    const int c  = i8 / 1000;                        // 8000/8 threads per channel
    const float mean  = bn_sum[c]   * (1.f / 8000.f);
    const float var   = bn_sumsq[c] * (1.f / 8000.f) - mean * mean;
    const float rstd  = rsqrtf(var + 1e-5f);
    const float scale = bn_w[c] * rstd;
    const float shift = bn_b[c] - mean * scale;

    union { int4 iv; __bf16 b[8]; } y;
    y.iv = reinterpret_cast<const int4*>(y_bf)[i8];
    float4 x0 = reinterpret_cast<const float4*>(x)[i8 * 2];
    float4 x1 = reinterpret_cast<const float4*>(x)[i8 * 2 + 1];

    float4 o0, o1;
    o0.x = fmaxf((float)y.b[0] * scale + shift, 0.f) + x0.x;
    o0.y = fmaxf((float)y.b[1] * scale + shift, 0.f) + x0.y;
    o0.z = fmaxf((float)y.b[2] * scale + shift, 0.f) + x0.z;
    o0.w = fmaxf((float)y.b[3] * scale + shift, 0.f) + x0.w;
    o1.x = fmaxf((float)y.b[4] * scale + shift, 0.f) + x1.x;
    o1.y = fmaxf((float)y.b[5] * scale + shift, 0.f) + x1.y;
    o1.z = fmaxf((float)y.b[6] * scale + shift, 0.f) + x1.z;
    o1.w = fmaxf((float)y.b[7] * scale + shift, 0.f) + x1.w;
    reinterpret_cast<float4*>(out)[i8 * 2]     = o0;
    reinterpret_cast<float4*>(out)[i8 * 2 + 1] = o1;
}

// ---------------------------------------------------------------------------
extern "C" void kernel_launch(void* const* d_in, const int* in_sizes, int n_in,
                              void* d_out, int out_size, void* d_ws, size_t ws_size,
                              hipStream_t stream)
{
    const float* x    = (const float*)d_in[0];
    const float* wq   = (const float*)d_in[1];
    const float* bq   = (const float*)d_in[2];
    const float* wk   = (const float*)d_in[3];
    const float* bk   = (const float*)d_in[4];
    const float* wv   = (const float*)d_in[5];
    const float* bv   = (const float*)d_in[6];
    const float* wa   = (const float*)d_in[7];
    const float* ba   = (const float*)d_in[8];
    const float* bn_w = (const float*)d_in[9];
    const float* bn_b = (const float*)d_in[10];
    float* out = (float*)d_out;

    char* base = (char*)d_ws;
    // byte layout (~15.1 MB):
    __bf16* av_part = (__bf16*)base;                   // 10,240,000 B (5 x 8000 x 128 bf16)
    __bf16* q_bf    = (__bf16*)(base + 10240000);      //    256,000 B
    __bf16* k_bf    = (__bf16*)(base + 10496000);      //    256,000 B
    __bf16* v_bf    = (__bf16*)(base + 10752000);      //  2,048,000 B
    float*  l_part  = (float*)(base + 12800000);       //    160,000 B
    float*  bn_sum   = (float*)(base + 12960000);      //        512 B
    float*  bn_sumsq = bn_sum + 128;                   //        512 B
    __bf16* y_bf    = (__bf16*)(base + 12961024);      //  2,048,000 B
    __bf16* w_frag  = (__bf16*)(base + 15009024);      //     73,728 B (4608 chunks)
    __bf16* wa_frag = w_frag + 2560 * 8;               //  (chunks 2560..4607)

    wcvt_kernel<<<18, 256, 0, stream>>>(wq, wk, wv, wa, w_frag, bn_sum);
    qkv_kernel<<<250, 256, 0, stream>>>(x, w_frag, bq, bk, bv, q_bf, k_bf, v_bf);
    attn_kernel<<<QTILES * KSPLIT, 256, 0, stream>>>(q_bf, k_bf, v_bf, av_part, l_part);
    proj_out_kernel<<<250, 256, 0, stream>>>(av_part, l_part, wa_frag, ba, y_bf, bn_sum, bn_sumsq);
    bn_relu_kernel<<<500, 256, 0, stream>>>(y_bf, x, bn_sum, bn_sumsq, bn_w, bn_b, out);
}

// Round 14
// 154.023 us; speedup vs baseline: 1.5750x; 1.0103x over previous
//
#include <hip/hip_runtime.h>
#include <math.h>

#define N_POS 8000
#define C_CH  128
#define KSPLIT 5
#define KT_PER 25      // 125 k-tiles of 64 keys, 25 per split
#define QTILES 125     // q-tiles of 64 queries

typedef __bf16 bf16x8 __attribute__((ext_vector_type(8)));
typedef float  f32x4  __attribute__((ext_vector_type(4)));

#define MFMA(a,b,c) __builtin_amdgcn_mfma_f32_16x16x32_bf16((a),(b),(c),0,0,0)

// MFMA 16x16x32 lane layouts (verified m89/m120):
//   A[m][k]: m = lane&15, k = (lane>>4)*8 + j
//   B[k][n]: n = lane&15, k = (lane>>4)*8 + j
//   D[m][n]: n = lane&15, m = (lane>>4)*4 + reg

#define GLOAD_LDS(gp, lp) \
    __builtin_amdgcn_global_load_lds( \
        (const __attribute__((address_space(1))) void*)(gp), \
        (__attribute__((address_space(3))) void*)(lp), 16, 0, 0)

// ---------------------------------------------------------------------------
// Kernel W: one-time weight repack fp32 -> fragment-ordered bf16, and
// (block 0) zeroing of bn_sum/bn_sumsq (folds the memset dispatch away).
// Chunk g = (mtg*4 + ks)*64 + lane holds A-frag bf16x8 for (mtile,ks,lane).
// mtg 0..9 = stacked {wq, wk, wv(8 tiles)}; mtg 10..17 = wa (8 tiles).
// ---------------------------------------------------------------------------
__global__ __launch_bounds__(256) void wcvt_kernel(
    const float* __restrict__ wq, const float* __restrict__ wk,
    const float* __restrict__ wv, const float* __restrict__ wa,
    __bf16* __restrict__ w_frag, float* __restrict__ bn_clear)
{
    if (blockIdx.x == 0) bn_clear[threadIdx.x] = 0.f;   // 256 floats = sum+sumsq

    const int g = blockIdx.x * 256 + threadIdx.x;   // 0..4607
    if (g >= 4608) return;
    const int mtg  = g >> 8;          // 0..17
    const int ks   = (g >> 6) & 3;
    const int lane = g & 63;
    const int l15  = lane & 15;
    const int quad = lane >> 4;

    const float* wrow;
    if (mtg == 0)       wrow = wq + l15 * 128;
    else if (mtg == 1)  wrow = wk + l15 * 128;
    else if (mtg < 10)  wrow = wv + ((mtg - 2) * 16 + l15) * 128;
    else                wrow = wa + ((mtg - 10) * 16 + l15) * 128;

    float4 f0 = *reinterpret_cast<const float4*>(wrow + ks * 32 + quad * 8);
    float4 f1 = *reinterpret_cast<const float4*>(wrow + ks * 32 + quad * 8 + 4);
    union { int4 iv; __bf16 b[8]; } u;
    u.b[0]=(__bf16)f0.x; u.b[1]=(__bf16)f0.y; u.b[2]=(__bf16)f0.z; u.b[3]=(__bf16)f0.w;
    u.b[4]=(__bf16)f1.x; u.b[5]=(__bf16)f1.y; u.b[6]=(__bf16)f1.z; u.b[7]=(__bf16)f1.w;
    *reinterpret_cast<int4*>(&w_frag[(size_t)g * 8]) = u.iv;
}

// ---------------------------------------------------------------------------
// Kernel A: QKV projections via MFMA. grid 250 (n-tiles of 32), block 256.
// (round-9 version: w_frag coalesced A-frags + 4-deep x load ILP.)
// out rows: o 0..15 -> q, 16..31 -> k, 32..159 -> v(ch=o-32)
// ---------------------------------------------------------------------------
__global__ __launch_bounds__(256) void qkv_kernel(
    const float* __restrict__ x, const __bf16* __restrict__ w_frag,
    const float* __restrict__ bq, const float* __restrict__ bk,
    const float* __restrict__ bv,
    __bf16* __restrict__ q_bf, __bf16* __restrict__ k_bf, __bf16* __restrict__ v_bf)
{
    __shared__ __bf16 x_lds[32 * 136];          // [n][c]
    __shared__ __bf16 v_out[128 * 36];          // [ch][n]

    const int t    = threadIdx.x;
    const int n0   = blockIdx.x * 32;
    const int lane = t & 63;
    const int w    = t >> 6;
    const int l15  = lane & 15;
    const int quad = lane >> 4;

    // stage x tile [128c x 32n] -> x_lds[n][c] bf16; 4 loads in flight first
    float4 xv[4];
#pragma unroll
    for (int r = 0; r < 4; ++r) {
        int f = r * 256 + t;
        int ch = f >> 3, n4 = f & 7;
        xv[r] = *reinterpret_cast<const float4*>(&x[ch * N_POS + n0 + n4 * 4]);
    }
#pragma unroll
    for (int r = 0; r < 4; ++r) {
        int f = r * 256 + t;
        int ch = f >> 3, n4 = f & 7;
        x_lds[(n4 * 4 + 0) * 136 + ch] = (__bf16)xv[r].x;
        x_lds[(n4 * 4 + 1) * 136 + ch] = (__bf16)xv[r].y;
        x_lds[(n4 * 4 + 2) * 136 + ch] = (__bf16)xv[r].z;
        x_lds[(n4 * 4 + 3) * 136 + ch] = (__bf16)xv[r].w;
    }

    // A-frags: coalesced from w_frag. wave w owns mtiles {w, w+4, w+8<10}
    bf16x8 aw[3][4];
    f32x4  acc[3][2];
    const int nmt = (w < 2) ? 3 : 2;
    for (int mi = 0; mi < nmt; ++mi) {
        int mt = w + 4 * mi;
        for (int ks = 0; ks < 4; ++ks)
            aw[mi][ks] = *reinterpret_cast<const bf16x8*>(
                &w_frag[(size_t)((mt * 4 + ks) * 64 + lane) * 8]);
        const float* brow;
        if (mt == 0)      brow = bq;
        else if (mt == 1) brow = bk;
        else              brow = bv + (mt - 2) * 16;
        for (int ni = 0; ni < 2; ++ni) {
            acc[mi][ni][0] = brow[quad * 4 + 0]; acc[mi][ni][1] = brow[quad * 4 + 1];
            acc[mi][ni][2] = brow[quad * 4 + 2]; acc[mi][ni][3] = brow[quad * 4 + 3];
        }
    }
    __syncthreads();

    for (int ks = 0; ks < 4; ++ks) {
        bf16x8 b0 = *reinterpret_cast<const bf16x8*>(&x_lds[(0  + l15) * 136 + ks * 32 + quad * 8]);
        bf16x8 b1 = *reinterpret_cast<const bf16x8*>(&x_lds[(16 + l15) * 136 + ks * 32 + quad * 8]);
        for (int mi = 0; mi < nmt; ++mi) {
            acc[mi][0] = MFMA(aw[mi][ks], b0, acc[mi][0]);
            acc[mi][1] = MFMA(aw[mi][ks], b1, acc[mi][1]);
        }
    }

    union S4 { short4 s; __bf16 b[4]; };
    for (int mi = 0; mi < nmt; ++mi) {
        int mt = w + 4 * mi;
        for (int ni = 0; ni < 2; ++ni) {
            S4 u;
            u.b[0]=(__bf16)acc[mi][ni][0]; u.b[1]=(__bf16)acc[mi][ni][1];
            u.b[2]=(__bf16)acc[mi][ni][2]; u.b[3]=(__bf16)acc[mi][ni][3];
            int n = n0 + ni * 16 + l15;
            if (mt == 0) {
                *reinterpret_cast<short4*>(&q_bf[n * 16 + quad * 4]) = u.s;
            } else if (mt == 1) {
                *reinterpret_cast<short4*>(&k_bf[n * 16 + quad * 4]) = u.s;
            } else {
                int ch0 = (mt - 2) * 16 + quad * 4;
                int nl  = ni * 16 + l15;
                v_out[(ch0 + 0) * 36 + nl] = u.b[0];
                v_out[(ch0 + 1) * 36 + nl] = u.b[1];
                v_out[(ch0 + 2) * 36 + nl] = u.b[2];
                v_out[(ch0 + 3) * 36 + nl] = u.b[3];
            }
        }
    }
    __syncthreads();
    for (int r = 0; r < 4; ++r) {
        int f = r * 256 + t;
        int ch = f >> 3, n4 = f & 7;
        int2 d = *reinterpret_cast<const int2*>(&v_out[ch * 36 + n4 * 4]);
        *reinterpret_cast<int2*>(&v_bf[ch * N_POS + n0 + n4 * 4]) = d;
    }
}

// ---------------------------------------------------------------------------
// Kernel B: fused attention, split-K, MFMA, global_load_lds double-buffer.
// (round-12 verified version: round-1 core + bf16 av partials, ~37 us.
// v13's K-in-regs + register l-sum FAILED correctness on HW despite
// address-identical dataflow -- reverted; do not re-attempt without a
// split A/B test.)
// ---------------------------------------------------------------------------
__global__ __launch_bounds__(256, 3) void attn_kernel(
    const __bf16* __restrict__ q_bf, const __bf16* __restrict__ k_bf,
    const __bf16* __restrict__ v_bf, __bf16* __restrict__ av_part,
    float* __restrict__ l_part)
{
    __shared__ __bf16 v_buf[2][8192];   // 16 KB each
    __shared__ __bf16 k_buf[2][1024];   // 2 KB each
    __shared__ __bf16 p_lds[4096];      // 8 KB; total 45056 B -> 3 blocks/CU

    const int t    = threadIdx.x;
    const int qt   = blockIdx.x % QTILES;
    const int sp   = blockIdx.x / QTILES;
    const int n0q  = qt * 64;
    const int lane = t & 63;
    const int w    = t >> 6;
    const int l15  = lane & 15;
    const int quad = lane >> 4;

    // staging maps (per lane, loop-invariant)
    const int chL   = lane >> 3;              // V: low 3 bits of channel
    const int vpart = (lane & 7) ^ chL;       // V: key-octet (XOR swizzle)
    const int kkey  = lane >> 1;              // K: key within 32-key half
    const int khalf = lane & 1;               // K: dim half

    // Q B-frags in registers (k-dim 16 padded to 32 with zeros), 4 q-groups
    bf16x8 aq[4];
    for (int ni = 0; ni < 4; ++ni) {
        for (int j = 0; j < 8; ++j) aq[ni][j] = (__bf16)0.0f;
        if (quad < 2)
            aq[ni] = *reinterpret_cast<const bf16x8*>(
                &q_bf[(n0q + ni * 16 + l15) * 16 + quad * 8]);
    }
    bf16x8 ones;
    for (int j = 0; j < 8; ++j) ones[j] = (__bf16)1.0f;

    f32x4 acc[2][4];
    for (int mi = 0; mi < 2; ++mi)
        for (int ni = 0; ni < 4; ++ni)
            for (int r = 0; r < 4; ++r) acc[mi][ni][r] = 0.f;
    f32x4 lacc;
    for (int r = 0; r < 4; ++r) lacc[r] = 0.f;

    const int kt0 = sp * KT_PER;

    // issue one tile's staging DMA: 4 V ops per wave; K ops on waves 0,1 only
    auto stage = [&](int kt, int buf) {
        const int n0k = kt * 64;
        for (int r = 0; r < 4; ++r) {
            int R = w * 4 + r;   // wave-uniform LDS base
            GLOAD_LDS(v_bf + (8 * R + chL) * N_POS + n0k + vpart * 8,
                      &v_buf[buf][R * 512]);
        }
        if (w < 2)
            GLOAD_LDS(k_bf + (size_t)(n0k + w * 32 + kkey) * 16 + khalf * 8,
                      &k_buf[buf][w * 512]);
    };

    stage(kt0, 0);

    const int oS  = w * 2 + (quad >> 1);   // P-write octet
    const int sub = (quad & 1) * 4;        // P-write elem offset in chunk

    union S4 { short4 sh; __bf16 b[4]; };

    for (int kt = kt0; kt < kt0 + KT_PER; ++kt) {
        const int cur = (kt - kt0) & 1;
        __syncthreads();   // barrier_A: vmcnt(0) drain of tile-kt DMA (1 iter of cover)

        // issue next tile's DMA NOW -> in flight across S + barrier_B + PV
        if (kt + 1 < kt0 + KT_PER) stage(kt + 1, cur ^ 1);

        // ---- S phase: A = K rows (wave w -> keys w*16..+15), B = Q regs
        bf16x8 ak;
        for (int j = 0; j < 8; ++j) ak[j] = (__bf16)0.0f;
        if (quad < 2)
            ak = *reinterpret_cast<const bf16x8*>(
                &k_buf[cur][(w * 16 + l15) * 16 + quad * 8]);
#pragma unroll
        for (int ni = 0; ni < 4; ++ni) {
            f32x4 s;
            for (int r = 0; r < 4; ++r) s[r] = 0.f;
            s = MFMA(ak, aq[ni], s);           // D[m=key][n=q]
            S4 u;
            u.b[0] = (__bf16)__expf(s[0]); u.b[1] = (__bf16)__expf(s[1]);
            u.b[2] = (__bf16)__expf(s[2]); u.b[3] = (__bf16)__expf(s[3]);
            *reinterpret_cast<short4*>(
                &p_lds[(oS * 64 + ni * 16 + l15) * 8 + sub]) = u.sh;
        }

        // barrier_B: P visible; DOES NOT drain vmcnt -> kt+1 DMA stays in flight
        asm volatile("s_waitcnt lgkmcnt(0)" ::: "memory");
        __builtin_amdgcn_s_barrier();
        asm volatile("" ::: "memory");
        __builtin_amdgcn_sched_barrier(0);

        // ---- PV phase: wave w owns ch-tiles {2w, 2w+1}
        const int chl = l15 & 7;
#pragma unroll
        for (int ks = 0; ks < 2; ++ks) {
            int pz = ((ks * 4 + quad) ^ chl);
            bf16x8 a0 = *reinterpret_cast<const bf16x8*>(
                &v_buf[cur][(((2 * w)     * 2 + (l15 >> 3)) * 64 + chl * 8 + pz) * 8]);
            bf16x8 a1 = *reinterpret_cast<const bf16x8*>(
                &v_buf[cur][(((2 * w + 1) * 2 + (l15 >> 3)) * 64 + chl * 8 + pz) * 8]);
            const int ob = (ks * 4 + quad) * 64;
            bf16x8 p0 = *reinterpret_cast<const bf16x8*>(&p_lds[(ob +  0 + l15) * 8]);
            bf16x8 p1 = *reinterpret_cast<const bf16x8*>(&p_lds[(ob + 16 + l15) * 8]);
            bf16x8 p2 = *reinterpret_cast<const bf16x8*>(&p_lds[(ob + 32 + l15) * 8]);
            bf16x8 p3 = *reinterpret_cast<const bf16x8*>(&p_lds[(ob + 48 + l15) * 8]);
            acc[0][0] = MFMA(a0, p0, acc[0][0]);
            acc[0][1] = MFMA(a0, p1, acc[0][1]);
            acc[0][2] = MFMA(a0, p2, acc[0][2]);
            acc[0][3] = MFMA(a0, p3, acc[0][3]);
            acc[1][0] = MFMA(a1, p0, acc[1][0]);
            acc[1][1] = MFMA(a1, p1, acc[1][1]);
            acc[1][2] = MFMA(a1, p2, acc[1][2]);
            acc[1][3] = MFMA(a1, p3, acc[1][3]);
            // l-sum: wave w reduces its own q-group (balanced across waves)
            bf16x8 pw = *reinterpret_cast<const bf16x8*>(&p_lds[(ob + w * 16 + l15) * 8]);
            lacc = MFMA(ones, pw, lacc);
        }
    }

    // write av partials BF16: av_part[sp][n][c]
    __bf16* dst = av_part + (size_t)sp * 1024000;
    union S4b { short4 sh; __bf16 b[4]; };
    for (int mi = 0; mi < 2; ++mi)
        for (int ni = 0; ni < 4; ++ni) {
            int n  = n0q + ni * 16 + l15;
            int ch = (2 * w + mi) * 16 + quad * 4;
            S4b u;
            u.b[0] = (__bf16)acc[mi][ni][0];
            u.b[1] = (__bf16)acc[mi][ni][1];
            u.b[2] = (__bf16)acc[mi][ni][2];
            u.b[3] = (__bf16)acc[mi][ni][3];
            *reinterpret_cast<short4*>(&dst[n * 128 + ch]) = u.sh;
        }
    if (quad == 0)
        l_part[sp * N_POS + n0q + w * 16 + l15] = lacc[0];
}

// ---------------------------------------------------------------------------
// Kernel C: split-K reduce (bf16 partials) + normalize fused with
// y = wa @ av + ba (MFMA) + BN stats.  grid 250, n-tile 32, block 256.
// (round-11/12 version: bf16 y, fp32 stats.)
// ---------------------------------------------------------------------------
__global__ __launch_bounds__(256) void proj_out_kernel(
    const __bf16* __restrict__ av_part, const float* __restrict__ l_part,
    const __bf16* __restrict__ wa_frag, const float* __restrict__ ba,
    __bf16* __restrict__ y_bf, float* __restrict__ bn_sum, float* __restrict__ bn_sumsq)
{
    __shared__ __bf16 b_lds[4096];   // 32n x 128c fragment-packed, swizzled

    const int t    = threadIdx.x;
    const int n0   = blockIdx.x * 32;
    const int lane = t & 63;
    const int w    = t >> 6;
    const int l15  = lane & 15;
    const int quad = lane >> 4;

    // build normalized B tile: 512 c-octets, 2 per thread (coalesced reads)
    for (int r = 0; r < 2; ++r) {
        int g = r * 256 + t;
        int n = g >> 4, oc = g & 15;
        float l = 0.f;
#pragma unroll
        for (int s = 0; s < KSPLIT; ++s) l += l_part[s * N_POS + n0 + n];
        // gather the 5 bf16 octets first (independent loads), then unpack
        union B8 { int4 iv; __bf16 b[8]; } raw[KSPLIT];
#pragma unroll
        for (int s = 0; s < KSPLIT; ++s)
            raw[s].iv = *reinterpret_cast<const int4*>(
                av_part + (size_t)s * 1024000 + (n0 + n) * 128 + oc * 8);
        float a[8];
#pragma unroll
        for (int j = 0; j < 8; ++j) a[j] = 0.f;
#pragma unroll
        for (int s = 0; s < KSPLIT; ++s)
#pragma unroll
            for (int j = 0; j < 8; ++j) a[j] += (float)raw[s].b[j];
        float inv = 1.f / l;
        union { int4 iv; __bf16 b[8]; } u;
#pragma unroll
        for (int j = 0; j < 8; ++j) u.b[j] = (__bf16)(a[j] * inv);
        int A = (n >> 4) * 16 + oc;
        int slot = (n & 15) ^ (oc & 7);
        *reinterpret_cast<int4*>(&b_lds[(A * 16 + slot) * 8]) = u.iv;
    }

    // A-frags: wa mtiles {2w, 2w+1} from fragment-packed buffer (coalesced)
    bf16x8 aw[2][4];
    f32x4  acc[2][2];
    for (int mi = 0; mi < 2; ++mi) {
        int mt = 2 * w + mi;
        for (int ks = 0; ks < 4; ++ks)
            aw[mi][ks] = *reinterpret_cast<const bf16x8*>(
                &wa_frag[(size_t)((mt * 4 + ks) * 64 + lane) * 8]);
        for (int ni = 0; ni < 2; ++ni) {
            acc[mi][ni][0] = ba[mt * 16 + quad * 4 + 0];
            acc[mi][ni][1] = ba[mt * 16 + quad * 4 + 1];
            acc[mi][ni][2] = ba[mt * 16 + quad * 4 + 2];
            acc[mi][ni][3] = ba[mt * 16 + quad * 4 + 3];
        }
    }
    __syncthreads();

    for (int ks = 0; ks < 4; ++ks) {
        int oc = ks * 4 + quad;
        int slot = l15 ^ (oc & 7);
        bf16x8 b0 = *reinterpret_cast<const bf16x8*>(&b_lds[((0  + oc) * 16 + slot) * 8]);
        bf16x8 b1 = *reinterpret_cast<const bf16x8*>(&b_lds[((16 + oc) * 16 + slot) * 8]);
        for (int mi = 0; mi < 2; ++mi) {
            acc[mi][0] = MFMA(aw[mi][ks], b0, acc[mi][0]);
            acc[mi][1] = MFMA(aw[mi][ks], b1, acc[mi][1]);
        }
    }

    // y writes (bf16) [c][n] + BN partial stats (fp32)
    for (int mi = 0; mi < 2; ++mi) {
        for (int r = 0; r < 4; ++r) {
            int ch = (2 * w + mi) * 16 + quad * 4 + r;
            float v0 = acc[mi][0][r];
            float v1 = acc[mi][1][r];
            y_bf[ch * N_POS + n0 + 0  + l15] = (__bf16)v0;
            y_bf[ch * N_POS + n0 + 16 + l15] = (__bf16)v1;
            float s1 = v0 + v1;
            float s2 = v0 * v0 + v1 * v1;
#pragma unroll
            for (int off = 8; off >= 1; off >>= 1) {
                s1 += __shfl_xor(s1, off, 64);
                s2 += __shfl_xor(s2, off, 64);
            }
            if (l15 == 0) {
                atomicAdd(&bn_sum[ch],   s1);
                atomicAdd(&bn_sumsq[ch], s2);
            }
        }
    }
}

// ---------------------------------------------------------------------------
// Kernel D: BatchNorm (training stats) + ReLU + residual. grid 500, block 256.
// (round-11/12 version: bf16 y read as int4, 8 elems/thread.)
// ---------------------------------------------------------------------------
__global__ __launch_bounds__(256) void bn_relu_kernel(
    const __bf16* __restrict__ y_bf, const float* __restrict__ x,
    const float* __restrict__ bn_sum, const float* __restrict__ bn_sumsq,
    const float* __restrict__ bn_w, const float* __restrict__ bn_b,
    float* __restrict__ out)
{
    const int i8 = blockIdx.x * 256 + threadIdx.x;   // 0..127999 (8 elems each)
    const int c  = i8 / 1000;                        // 8000/8 threads per channel
    const float mean  = bn_sum[c]   * (1.f / 8000.f);
    const float var   = bn_sumsq[c] * (1.f / 8000.f) - mean * mean;
    const float rstd  = rsqrtf(var + 1e-5f);
    const float scale = bn_w[c] * rstd;
    const float shift = bn_b[c] - mean * scale;

    union { int4 iv; __bf16 b[8]; } y;
    y.iv = reinterpret_cast<const int4*>(y_bf)[i8];
    float4 x0 = reinterpret_cast<const float4*>(x)[i8 * 2];
    float4 x1 = reinterpret_cast<const float4*>(x)[i8 * 2 + 1];

    float4 o0, o1;
    o0.x = fmaxf((float)y.b[0] * scale + shift, 0.f) + x0.x;
    o0.y = fmaxf((float)y.b[1] * scale + shift, 0.f) + x0.y;
    o0.z = fmaxf((float)y.b[2] * scale + shift, 0.f) + x0.z;
    o0.w = fmaxf((float)y.b[3] * scale + shift, 0.f) + x0.w;
    o1.x = fmaxf((float)y.b[4] * scale + shift, 0.f) + x1.x;
    o1.y = fmaxf((float)y.b[5] * scale + shift, 0.f) + x1.y;
    o1.z = fmaxf((float)y.b[6] * scale + shift, 0.f) + x1.z;
    o1.w = fmaxf((float)y.b[7] * scale + shift, 0.f) + x1.w;
    reinterpret_cast<float4*>(out)[i8 * 2]     = o0;
    reinterpret_cast<float4*>(out)[i8 * 2 + 1] = o1;
}

// ---------------------------------------------------------------------------
extern "C" void kernel_launch(void* const* d_in, const int* in_sizes, int n_in,
                              void* d_out, int out_size, void* d_ws, size_t ws_size,
                              hipStream_t stream)
{
    const float* x    = (const float*)d_in[0];
    const float* wq   = (const float*)d_in[1];
    const float* bq   = (const float*)d_in[2];
    const float* wk   = (const float*)d_in[3];
    const float* bk   = (const float*)d_in[4];
    const float* wv   = (const float*)d_in[5];
    const float* bv   = (const float*)d_in[6];
    const float* wa   = (const float*)d_in[7];
    const float* ba   = (const float*)d_in[8];
    const float* bn_w = (const float*)d_in[9];
    const float* bn_b = (const float*)d_in[10];
    float* out = (float*)d_out;

    char* base = (char*)d_ws;
    // byte layout (~15.1 MB):
    __bf16* av_part = (__bf16*)base;                   // 10,240,000 B (5 x 8000 x 128 bf16)
    __bf16* q_bf    = (__bf16*)(base + 10240000);      //    256,000 B
    __bf16* k_bf    = (__bf16*)(base + 10496000);      //    256,000 B
    __bf16* v_bf    = (__bf16*)(base + 10752000);      //  2,048,000 B
    float*  l_part  = (float*)(base + 12800000);       //    160,000 B
    float*  bn_sum   = (float*)(base + 12960000);      //        512 B
    float*  bn_sumsq = bn_sum + 128;                   //        512 B
    __bf16* y_bf    = (__bf16*)(base + 12961024);      //  2,048,000 B
    __bf16* w_frag  = (__bf16*)(base + 15009024);      //     73,728 B (4608 chunks)
    __bf16* wa_frag = w_frag + 2560 * 8;               //  (chunks 2560..4607)

    wcvt_kernel<<<18, 256, 0, stream>>>(wq, wk, wv, wa, w_frag, bn_sum);
    qkv_kernel<<<250, 256, 0, stream>>>(x, w_frag, bq, bk, bv, q_bf, k_bf, v_bf);
    attn_kernel<<<QTILES * KSPLIT, 256, 0, stream>>>(q_bf, k_bf, v_bf, av_part, l_part);
    proj_out_kernel<<<250, 256, 0, stream>>>(av_part, l_part, wa_frag, ba, y_bf, bn_sum, bn_sumsq);
    bn_relu_kernel<<<500, 256, 0, stream>>>(y_bf, x, bn_sum, bn_sumsq, bn_w, bn_b, out);
}